// Round 8
// baseline (212.795 us; speedup 1.0000x reference)
//
#include <hip/hip_runtime.h>
#include <hip/hip_bf16.h>
#include <math.h>

// Problem constants
#define BATCH   8
#define S_LEN   1024
#define D_MODEL 1280
#define DX      768
#define NH      8
#define HD      160
#define LTXT    77
#define NBH     (BATCH*NH)      // 64
#define MKV_PAD 640             // 616 padded to 128-multiple
#define MQ      (BATCH*S_LEN)   // 8192
#define MKV     (BATCH*LTXT)    // 616

typedef _Float16 f16x8 __attribute__((ext_vector_type(8)));
typedef _Float16 f16x4 __attribute__((ext_vector_type(4)));
typedef float    f32x4 __attribute__((ext_vector_type(4)));

// ---------------------------------------------------------------------------
// Fused prep kernel: all input-only conversions in ONE launch.
//  J0: hidden fp32 [8192,1280] -> hidf f16
//  J1: enc fp32 [616,768] -> encb f16 [640,768] (pad rows zeroed)
//  J2: Wq^T  -> B2Tq  [1280][1280]
//  J3: Wo^T  -> B2To  [1280][1280]
//  J4: Wk^T  -> B2Tkv rows 0..1279   (stride 768)
//  J5: Wv^T  -> B2Tkv rows 1280..2559
// ---------------------------------------------------------------------------
#define NB_HID 10240   // 8192*1280/4/256
#define NB_ENC 480     // 640*768/4/256
#define NB_WQ  1600    // 40x40 32x32-tiles
#define NB_WO  1600
#define NB_WK  960     // 40x24
#define NB_WV  960
#define NB_PREP (NB_HID+NB_ENC+NB_WQ+NB_WO+NB_WK+NB_WV)

__device__ inline void to_f16_dev(const float* __restrict__ X,
                                  _Float16* __restrict__ Y,
                                  int K, int Mreal, int bid)
{
    const size_t g = ((size_t)bid * 256 + threadIdx.x) * 4;
    const int row = (int)(g / K);
    float4 x = make_float4(0.f, 0.f, 0.f, 0.f);
    if (row < Mreal) x = *(const float4*)&X[g];
    f16x4 o;
    o[0] = (_Float16)x.x; o[1] = (_Float16)x.y;
    o[2] = (_Float16)x.z; o[3] = (_Float16)x.w;
    *(f16x4*)&Y[g] = o;
}

__device__ inline void wt_t_dev(const float* __restrict__ W,
                                _Float16* __restrict__ BT,
                                int K, int N, int KLD, int noff,
                                int bx, int by, float (*tile)[33])
{
    const int k0 = by * 32, n0 = bx * 32;
    const int tx = threadIdx.x & 31, ty = threadIdx.x >> 5;
#pragma unroll
    for (int r = 0; r < 32; r += 8)
        tile[r + ty][tx] = W[(size_t)(k0 + r + ty) * N + n0 + tx];
    __syncthreads();
#pragma unroll
    for (int r = 0; r < 32; r += 8) {
        const int n = noff + n0 + r + ty, k = k0 + tx;
        BT[(size_t)n * KLD + k] = (_Float16)tile[tx][r + ty];
    }
}

__global__ __launch_bounds__(256) void prep_kernel(
    const float* __restrict__ hidden, const float* __restrict__ enc,
    const float* __restrict__ Wq, const float* __restrict__ Wk,
    const float* __restrict__ Wv, const float* __restrict__ Wo,
    _Float16* __restrict__ hidf, _Float16* __restrict__ encb,
    _Float16* __restrict__ B2Tq, _Float16* __restrict__ B2To,
    _Float16* __restrict__ B2Tkv)
{
    __shared__ float tile[32][33];
    int bid = blockIdx.x;
    if (bid < NB_HID) { to_f16_dev(hidden, hidf, D_MODEL, MQ, bid); return; }
    bid -= NB_HID;
    if (bid < NB_ENC) { to_f16_dev(enc, encb, DX, MKV, bid); return; }
    bid -= NB_ENC;
    if (bid < NB_WQ)  { wt_t_dev(Wq, B2Tq, D_MODEL, D_MODEL, D_MODEL, 0, bid % 40, bid / 40, tile); return; }
    bid -= NB_WQ;
    if (bid < NB_WO)  { wt_t_dev(Wo, B2To, D_MODEL, D_MODEL, D_MODEL, 0, bid % 40, bid / 40, tile); return; }
    bid -= NB_WO;
    if (bid < NB_WK)  { wt_t_dev(Wk, B2Tkv, DX, D_MODEL, DX, 0, bid % 40, bid / 40, tile); return; }
    bid -= NB_WK;
    wt_t_dev(Wv, B2Tkv, DX, D_MODEL, DX, D_MODEL, bid % 40, bid / 40, tile);
}

// ---------------------------------------------------------------------------
// MFMA fp16 GEMM device body, B^T layout: C[M,N] = A[M,KK] @ B[N,KK]^T (+bias)
// Proven round-6 structure: 128x128 tile, BK=64, 4 waves, single 32KB LDS,
// stage->barrier->compute->barrier, T2 swizzle, T1 bijective XCD swizzle.
// Output modes: kout!=0 -> K f16 / V fp32 split; Cb!=0 -> f16; else Cf fp32.
// ---------------------------------------------------------------------------
__device__ inline void async_copy16(const void* gptr, void* lptr) {
    __builtin_amdgcn_global_load_lds(
        (const __attribute__((address_space(1))) unsigned*)gptr,
        (__attribute__((address_space(3))) unsigned*)lptr, 16, 0, 0);
}

__device__ inline void gemm_body(
    const _Float16* __restrict__ A, const _Float16* __restrict__ B,
    float* __restrict__ Cf, _Float16* __restrict__ Cb,
    _Float16* __restrict__ kout, float* __restrict__ vout,
    int Mreal, int N, int KK, int ntn, const float* __restrict__ bias,
    int bid, int nwg, _Float16* As, _Float16* Bs)
{
    const int t = threadIdx.x;
    const int wave = t >> 6, lane = t & 63;
    const int lr = lane & 15, lg = lane >> 4;
    const int wr = wave >> 1, wc = wave & 1;

    // T1 bijective XCD-chunk swizzle (m204)
    const int q = nwg >> 3, r = nwg & 7;
    const int xcd = bid & 7, idx = bid >> 3;
    const int swz = (xcd < r ? xcd * (q + 1) : r * (q + 1) + (xcd - r) * q) + idx;
    const int m0 = (swz / ntn) * 128, n0 = (swz % ntn) * 128;

    f32x4 acc[4][4] = {};

    const int sr = lane >> 3;                   // row within staging instr
    const int sk = 8 * ((lane & 7) ^ sr);       // T2 pre-swizzled k-elem offset

    for (int k0 = 0; k0 < KK; k0 += 64) {
        __syncthreads();   // previous compute done
#pragma unroll
        for (int s = 0; s < 4; ++s) {
            const int ti = wave * 4 + s;
            const int row = ti * 8 + sr;
            async_copy16(A + (size_t)(m0 + row) * KK + k0 + sk, As + ti * 512);
            async_copy16(B + (size_t)(n0 + row) * KK + k0 + sk, Bs + ti * 512);
        }
        __syncthreads();   // staging complete (barrier drains vmcnt)

        f16x8 af[4][2], bf_[4][2];
#pragma unroll
        for (int i = 0; i < 4; ++i)
#pragma unroll
            for (int ki = 0; ki < 2; ++ki) {
                const int koff = (ki * 32 + lg * 8) ^ ((lr & 7) * 8);
                af[i][ki]  = *(const f16x8*)(As + (wr * 64 + i * 16 + lr) * 64 + koff);
                bf_[i][ki] = *(const f16x8*)(Bs + (wc * 64 + i * 16 + lr) * 64 + koff);
            }
#pragma unroll
        for (int ki = 0; ki < 2; ++ki)
#pragma unroll
            for (int i = 0; i < 4; ++i)
#pragma unroll
                for (int j = 0; j < 4; ++j)
                    acc[i][j] = __builtin_amdgcn_mfma_f32_16x16x32_f16(
                        af[i][ki], bf_[j][ki], acc[i][j], 0, 0, 0);
    }

    // epilogue: C row = lg*4 + rr, col = lr within fragment (m89 layout)
#pragma unroll
    for (int i = 0; i < 4; ++i) {
#pragma unroll
        for (int j = 0; j < 4; ++j) {
            const int col = n0 + wc * 64 + j * 16 + lr;
            const float bv = bias ? bias[col] : 0.f;
#pragma unroll
            for (int rr = 0; rr < 4; ++rr) {
                const int row = m0 + wr * 64 + i * 16 + lg * 4 + rr;
                const float v = acc[i][j][rr] + bv;
                if (kout) {
                    if (row < Mreal) {
                        if (col < D_MODEL) kout[(size_t)row * D_MODEL + col] = (_Float16)v;
                        else               vout[(size_t)row * D_MODEL + col - D_MODEL] = v;
                    }
                } else if (Cb) {
                    Cb[(size_t)row * N + col] = (_Float16)v;
                } else {
                    Cf[(size_t)row * N + col] = v;
                }
            }
        }
    }
}

// Mega-GEMM: Q projection (640 blocks) + fused K|V projection (100 blocks)
// in one launch -- KV blocks fill the Q job's grid tail.
#define GQ_BLOCKS  ((MQ/128)*(D_MODEL/128))            // 640
#define GKV_BLOCKS ((MKV_PAD/128)*(2*D_MODEL/128))     // 100

__global__ __launch_bounds__(256) void gemm_qkv(
    const _Float16* __restrict__ hidf, const _Float16* __restrict__ B2Tq,
    _Float16* __restrict__ qf,
    const _Float16* __restrict__ encb, const _Float16* __restrict__ B2Tkv,
    _Float16* __restrict__ kf, float* __restrict__ vbuf)
{
    __shared__ __align__(16) _Float16 As[128 * 64];
    __shared__ __align__(16) _Float16 Bs[128 * 64];
    if (blockIdx.x < GQ_BLOCKS)
        gemm_body(hidf, B2Tq, nullptr, qf, nullptr, nullptr,
                  MQ, D_MODEL, D_MODEL, D_MODEL / 128, nullptr,
                  blockIdx.x, GQ_BLOCKS, As, Bs);
    else
        gemm_body(encb, B2Tkv, nullptr, nullptr, kf, vbuf,
                  MKV, 2 * D_MODEL, DX, 2 * D_MODEL / 128, nullptr,
                  blockIdx.x - GQ_BLOCKS, GKV_BLOCKS, As, Bs);
}

__global__ __launch_bounds__(256) void gemm_out(
    const _Float16* __restrict__ hsf, const _Float16* __restrict__ B2To,
    float* __restrict__ out, const float* __restrict__ bo)
{
    __shared__ __align__(16) _Float16 As[128 * 64];
    __shared__ __align__(16) _Float16 Bs[128 * 64];
    gemm_body(hsf, B2To, out, nullptr, nullptr, nullptr,
              MQ, D_MODEL, D_MODEL, D_MODEL / 128, bo,
              blockIdx.x, GQ_BLOCKS, As, Bs);
}

// ---------------------------------------------------------------------------
// Ortho-decomp retain transform: reads fp32 V, writes f16 V (identical
// rounding point to before -- attn converted to f16 anyway).
// ---------------------------------------------------------------------------
__global__ __launch_bounds__(256) void retain_kernel(
    const float* __restrict__ vbuf, _Float16* __restrict__ vf16,
    const float* __restrict__ tv)
{
    const int l = blockIdx.x % LTXT;
    const int r = blockIdx.x / LTXT;
    const int t = threadIdx.x;

    float g00=0,g01=0,g02=0,g11=0,g12=0,g22=0,tp0=0,tp1=0,tp2=0,pp=0;
    float p_save[10], t0s[10], t1s[10], t2s[10];
#pragma unroll
    for (int it = 0; it < 10; ++it) {
        const int j   = t + it * 256;
        const int m16 = j / HD, d = j % HD;
        const int e = m16 >> 3, h = m16 & 7;
        const float T0 = tv[((size_t)(e*24 +  0 + h) * LTXT + l) * HD + d];
        const float T1 = tv[((size_t)(e*24 +  8 + h) * LTXT + l) * HD + d];
        const float T2 = tv[((size_t)(e*24 + 16 + h) * LTXT + l) * HD + d];
        const float p  = vbuf[((size_t)((e*4 + r) * LTXT + l)) * D_MODEL + h*HD + d];
        p_save[it] = p; t0s[it] = T0; t1s[it] = T1; t2s[it] = T2;
        g00 += T0*T0; g01 += T0*T1; g02 += T0*T2;
        g11 += T1*T1; g12 += T1*T2; g22 += T2*T2;
        tp0 += T0*p;  tp1 += T1*p;  tp2 += T2*p;  pp += p*p;
    }

    __shared__ float part[4][10];
    const int wave = t >> 6, lane = t & 63;
    float vals[10] = {g00,g01,g02,g11,g12,g22,tp0,tp1,tp2,pp};
#pragma unroll
    for (int i = 0; i < 10; ++i) {
        float x = vals[i];
        x += __shfl_down(x, 32); x += __shfl_down(x, 16);
        x += __shfl_down(x,  8); x += __shfl_down(x,  4);
        x += __shfl_down(x,  2); x += __shfl_down(x,  1);
        if (lane == 0) part[wave][i] = x;
    }
    __syncthreads();

    float s[10];
#pragma unroll
    for (int i = 0; i < 10; ++i)
        s[i] = part[0][i] + part[1][i] + part[2][i] + part[3][i];

    const float G[3][3] = {{s[0],s[1],s[2]},{s[1],s[3],s[4]},{s[2],s[4],s[5]}};
    const float tp[3] = {s[6], s[7], s[8]};
    const float ppv = s[9];

    float Pm[3][3];
#pragma unroll
    for (int c = 0; c < 3; ++c)
#pragma unroll
        for (int e = 0; e < 3; ++e) {
            float v = (c == e) ? 1.f : 0.f;
            if (c > e) v -= G[c][e] / G[e][e];
            Pm[c][e] = v;
        }

    const float nP = fmaxf(sqrtf(ppv), 1e-8f);
    float w[3], cosg[3];
#pragma unroll
    for (int c = 0; c < 3; ++c) {
        const float nT = fmaxf(sqrtf(G[c][c]), 1e-8f);
        const float cosv = tp[c] / (nT * nP);
        cosg[c] = 1.f / (1.f + expf(-10.f * (cosv - 0.5f)));
        float d1 = Pm[c][0]*tp[0] + Pm[c][1]*tp[1] + Pm[c][2]*tp[2];
        float d2 = 0.f;
#pragma unroll
        for (int e = 0; e < 3; ++e)
#pragma unroll
            for (int f = 0; f < 3; ++f) d2 += Pm[c][e] * Pm[c][f] * G[e][f];
        float wc = d1 / d2;
        if (isnan(wc)) wc = 0.f;
        if (l == 0)    wc = 0.f;
        w[c] = wc;
    }

    float coef[3];
#pragma unroll
    for (int e = 0; e < 3; ++e)
        coef[e] = cosg[e] * (w[0]*Pm[0][e] + w[1]*Pm[1][e] + w[2]*Pm[2][e]);

#pragma unroll
    for (int it = 0; it < 10; ++it) {
        const int j   = t + it * 256;
        const int m16 = j / HD, d = j % HD;
        const int e = m16 >> 3, h = m16 & 7;
        const float era = coef[0]*t0s[it] + coef[1]*t1s[it] + coef[2]*t2s[it];
        vf16[((size_t)((e*4 + r) * LTXT + l)) * D_MODEL + h*HD + d] =
            (_Float16)(p_save[it] - era);
    }
}

// ---------------------------------------------------------------------------
// MFMA attention (round-3 structure, fp16 K/V inputs -- half the staging
// bytes, no cvt VALU; identical numerics).
// ---------------------------------------------------------------------------
#define KSTRIDE 168
#define VSTRIDE 104
#define PSTRIDE 104

__global__ __launch_bounds__(256, 3) void attn_mfma(
    const _Float16* __restrict__ qb,     // [8192][1280] f16
    const _Float16* __restrict__ kf,     // [616][1280] f16
    const _Float16* __restrict__ vf,     // [616][1280] f16 (retained)
    _Float16* __restrict__ hs)           // [8192][1280] f16 out
{
    __shared__ _Float16 KV[160 * VSTRIDE];    // K view: [80][KSTRIDE]
    __shared__ _Float16 Ps[4][16 * PSTRIDE];
    const int bh = blockIdx.x, b = bh >> 3, h = bh & 7;
    const int qt = blockIdx.y;
    const int t = threadIdx.x, wave = t >> 6, lane = t & 63;
    const int lr = lane & 15, lg = lane >> 4;

    // stage K as [80][KSTRIDE] f16, rows >=77 zeroed (80 rows x 20 chunks of 8)
    for (int c = t; c < 1600; c += 256) {
        const int l = c / 20, d8 = (c % 20) * 8;
        f16x8 u;
#pragma unroll
        for (int i = 0; i < 8; ++i) u[i] = (_Float16)0.f;
        if (l < LTXT) u = *(const f16x8*)&kf[((size_t)(b * LTXT + l)) * D_MODEL + h * HD + d8];
        *(f16x8*)&KV[l * KSTRIDE + d8] = u;
    }
    {
        for (int i = lane; i < 256; i += 64)
            Ps[wave][(i >> 4) * PSTRIDE + 80 + (i & 15)] = (_Float16)0.f;
    }
    __syncthreads();

    const int qrow0 = b * S_LEN + qt * 64 + wave * 16;
    const _Float16* qp = qb + (size_t)(qrow0 + lr) * D_MODEL + h * HD;
    f16x8 af[5];
#pragma unroll
    for (int kt = 0; kt < 5; ++kt)
        af[kt] = *(const f16x8*)&qp[kt * 32 + lg * 8];

    f32x4 accs[5] = {};
#pragma unroll
    for (int j = 0; j < 5; ++j)
#pragma unroll
        for (int kt = 0; kt < 5; ++kt) {
            const f16x8 bf = *(const f16x8*)&KV[(j * 16 + lr) * KSTRIDE + kt * 32 + lg * 8];
            accs[j] = __builtin_amdgcn_mfma_f32_16x16x32_f16(af[kt], bf, accs[j], 0, 0, 0);
        }

    float s[5][4];
    const float scale = 0.07905694150420949f;  // 1/sqrt(160)
#pragma unroll
    for (int j = 0; j < 5; ++j)
#pragma unroll
        for (int r = 0; r < 4; ++r)
            s[j][r] = accs[j][r] * scale;
    if (lr >= 13) { s[4][0] = -1e30f; s[4][1] = -1e30f; s[4][2] = -1e30f; s[4][3] = -1e30f; }

    float rsum[4];
#pragma unroll
    for (int r = 0; r < 4; ++r) {
        float m = s[0][r];
#pragma unroll
        for (int j = 1; j < 5; ++j) m = fmaxf(m, s[j][r]);
        m = fmaxf(m, __shfl_xor(m, 1));
        m = fmaxf(m, __shfl_xor(m, 2));
        m = fmaxf(m, __shfl_xor(m, 4));
        m = fmaxf(m, __shfl_xor(m, 8));
        float sum = 0.f;
#pragma unroll
        for (int j = 0; j < 5; ++j) {
            const float p = __expf(s[j][r] - m);
            s[j][r] = p;
            sum += p;
        }
        sum += __shfl_xor(sum, 1);
        sum += __shfl_xor(sum, 2);
        sum += __shfl_xor(sum, 4);
        sum += __shfl_xor(sum, 8);
        rsum[r] = sum;
    }

#pragma unroll
    for (int j = 0; j < 5; ++j)
#pragma unroll
        for (int r = 0; r < 4; ++r)
            Ps[wave][(lg * 4 + r) * PSTRIDE + j * 16 + lr] = (_Float16)s[j][r];

    __syncthreads();   // all waves done reading K view of KV

    // stage V^T as [160][VSTRIDE] f16, key cols >=77 zeroed (96 rows x 20 chunks)
    for (int c = t; c < 1920; c += 256) {
        const int l = c / 20, d8 = (c % 20) * 8;
        f16x8 vv;
#pragma unroll
        for (int i = 0; i < 8; ++i) vv[i] = (_Float16)0.f;
        if (l < LTXT) vv = *(const f16x8*)&vf[((size_t)(b * LTXT + l)) * D_MODEL + h * HD + d8];
#pragma unroll
        for (int i = 0; i < 8; ++i)
            KV[(d8 + i) * VSTRIDE + l] = vv[i];
    }
    __syncthreads();

    f16x8 pa[3];
#pragma unroll
    for (int kt = 0; kt < 3; ++kt)
        pa[kt] = *(const f16x8*)&Ps[wave][lr * PSTRIDE + kt * 32 + lg * 8];
    f32x4 acch[10] = {};
#pragma unroll
    for (int dt = 0; dt < 10; ++dt)
#pragma unroll
        for (int kt = 0; kt < 3; ++kt) {
            const f16x8 vb = *(const f16x8*)&KV[(dt * 16 + lr) * VSTRIDE + kt * 32 + lg * 8];
            acch[dt] = __builtin_amdgcn_mfma_f32_16x16x32_f16(pa[kt], vb, acch[dt], 0, 0, 0);
        }

    const float inv[4] = {1.f / rsum[0], 1.f / rsum[1], 1.f / rsum[2], 1.f / rsum[3]};
#pragma unroll
    for (int dt = 0; dt < 10; ++dt) {
        const int col = h * HD + dt * 16 + lr;
#pragma unroll
        for (int r = 0; r < 4; ++r) {
            const int row = qrow0 + lg * 4 + r;
            hs[(size_t)row * D_MODEL + col] = (_Float16)(acch[dt][r] * inv[r]);
        }
    }
}

// ---------------------------------------------------------------------------
extern "C" void kernel_launch(void* const* d_in, const int* in_sizes, int n_in,
                              void* d_out, int out_size, void* d_ws, size_t ws_size,
                              hipStream_t stream)
{
    const float* hidden = (const float*)d_in[0]; // [8,1024,1280]
    const float* enc    = (const float*)d_in[1]; // [8,77,768]
    const float* Wq     = (const float*)d_in[2]; // [1280,1280]
    const float* Wk     = (const float*)d_in[3]; // [768,1280]
    const float* Wv     = (const float*)d_in[4]; // [768,1280]
    const float* Wo     = (const float*)d_in[5]; // [1280,1280]
    const float* bo     = (const float*)d_in[6]; // [1280]
    const float* tv     = (const float*)d_in[7]; // [48,77,160]
    float* out = (float*)d_out;

    // ws layout (~81 MB, all 16B-aligned boundaries)
    _Float16* kf     = (_Float16*)d_ws;                        // [616,1280] f16 K
    float*    vbuf   = (float*)(kf + (size_t)MKV * D_MODEL);   // [616,1280] f32 V (pre-retain)
    _Float16* vf16   = (_Float16*)(vbuf + (size_t)MKV * D_MODEL); // [616,1280] f16 V (retained)
    _Float16* qf     = vf16 + (size_t)MKV * D_MODEL;           // [8192,1280]
    _Float16* hsf    = qf   + (size_t)MQ * D_MODEL;            // [8192,1280]
    _Float16* hidf   = hsf  + (size_t)MQ * D_MODEL;            // [8192,1280]
    _Float16* encb   = hidf + (size_t)MQ * D_MODEL;            // [640,768]
    _Float16* B2Tq   = encb + (size_t)MKV_PAD * DX;            // [1280,1280]
    _Float16* B2To   = B2Tq + (size_t)D_MODEL * D_MODEL;       // [1280,1280]
    _Float16* B2Tkv  = B2To + (size_t)D_MODEL * D_MODEL;       // [2560,768]

    // 1. all input conversions/transposes in one launch
    prep_kernel<<<NB_PREP, 256, 0, stream>>>(
        hidden, enc, Wq, Wk, Wv, Wo, hidf, encb, B2Tq, B2To, B2Tkv);

    // 2. Q projection + fused K|V projection in one launch (KV fills Q's tail)
    gemm_qkv<<<GQ_BLOCKS + GKV_BLOCKS, 256, 0, stream>>>(
        hidf, B2Tq, qf, encb, B2Tkv, kf, vbuf);

    // 3. concept-erasure retain transform: fp32 V -> f16 V
    retain_kernel<<<4 * LTXT, 256, 0, stream>>>(vbuf, vf16, tv);

    // 4. MFMA attention (f16 K/V): writes hs f16
    attn_mfma<<<dim3(NBH, S_LEN / 64), 256, 0, stream>>>(qf, kf, vf16, hsf);

    // 5. out = hs @ Wo + bo
    gemm_out<<<GQ_BLOCKS, 256, 0, stream>>>(hsf, B2To, out, bo);
}

// Round 9
// 212.273 us; speedup vs baseline: 1.0025x; 1.0025x over previous
//
#include <hip/hip_runtime.h>
#include <hip/hip_bf16.h>
#include <math.h>

// Problem constants
#define BATCH   8
#define S_LEN   1024
#define D_MODEL 1280
#define DX      768
#define NH      8
#define HD      160
#define LTXT    77
#define NBH     (BATCH*NH)      // 64
#define MKV_PAD 640             // 616 padded to 128-multiple
#define MQ      (BATCH*S_LEN)   // 8192
#define MKV     (BATCH*LTXT)    // 616

typedef _Float16 f16x8 __attribute__((ext_vector_type(8)));
typedef _Float16 f16x4 __attribute__((ext_vector_type(4)));
typedef float    f32x4 __attribute__((ext_vector_type(4)));

// ---------------------------------------------------------------------------
// Fused prep kernel: all input-only conversions in ONE launch.
// ---------------------------------------------------------------------------
#define NB_HID 10240   // 8192*1280/4/256
#define NB_ENC 480     // 640*768/4/256
#define NB_WQ  1600    // 40x40 32x32-tiles
#define NB_WO  1600
#define NB_WK  960     // 40x24
#define NB_WV  960
#define NB_PREP (NB_HID+NB_ENC+NB_WQ+NB_WO+NB_WK+NB_WV)

__device__ inline void to_f16_dev(const float* __restrict__ X,
                                  _Float16* __restrict__ Y,
                                  int K, int Mreal, int bid)
{
    const size_t g = ((size_t)bid * 256 + threadIdx.x) * 4;
    const int row = (int)(g / K);
    float4 x = make_float4(0.f, 0.f, 0.f, 0.f);
    if (row < Mreal) x = *(const float4*)&X[g];
    f16x4 o;
    o[0] = (_Float16)x.x; o[1] = (_Float16)x.y;
    o[2] = (_Float16)x.z; o[3] = (_Float16)x.w;
    *(f16x4*)&Y[g] = o;
}

__device__ inline void wt_t_dev(const float* __restrict__ W,
                                _Float16* __restrict__ BT,
                                int K, int N, int KLD, int noff,
                                int bx, int by, float (*tile)[33])
{
    const int k0 = by * 32, n0 = bx * 32;
    const int tx = threadIdx.x & 31, ty = threadIdx.x >> 5;
#pragma unroll
    for (int r = 0; r < 32; r += 8)
        tile[r + ty][tx] = W[(size_t)(k0 + r + ty) * N + n0 + tx];
    __syncthreads();
#pragma unroll
    for (int r = 0; r < 32; r += 8) {
        const int n = noff + n0 + r + ty, k = k0 + tx;
        BT[(size_t)n * KLD + k] = (_Float16)tile[tx][r + ty];
    }
}

__global__ __launch_bounds__(256) void prep_kernel(
    const float* __restrict__ hidden, const float* __restrict__ enc,
    const float* __restrict__ Wq, const float* __restrict__ Wk,
    const float* __restrict__ Wv, const float* __restrict__ Wo,
    _Float16* __restrict__ hidf, _Float16* __restrict__ encb,
    _Float16* __restrict__ B2Tq, _Float16* __restrict__ B2To,
    _Float16* __restrict__ B2Tkv)
{
    __shared__ float tile[32][33];
    int bid = blockIdx.x;
    if (bid < NB_HID) { to_f16_dev(hidden, hidf, D_MODEL, MQ, bid); return; }
    bid -= NB_HID;
    if (bid < NB_ENC) { to_f16_dev(enc, encb, DX, MKV, bid); return; }
    bid -= NB_ENC;
    if (bid < NB_WQ)  { wt_t_dev(Wq, B2Tq, D_MODEL, D_MODEL, D_MODEL, 0, bid % 40, bid / 40, tile); return; }
    bid -= NB_WQ;
    if (bid < NB_WO)  { wt_t_dev(Wo, B2To, D_MODEL, D_MODEL, D_MODEL, 0, bid % 40, bid / 40, tile); return; }
    bid -= NB_WO;
    if (bid < NB_WK)  { wt_t_dev(Wk, B2Tkv, DX, D_MODEL, DX, 0, bid % 40, bid / 40, tile); return; }
    bid -= NB_WK;
    wt_t_dev(Wv, B2Tkv, DX, D_MODEL, DX, D_MODEL, bid % 40, bid / 40, tile);
}

// ---------------------------------------------------------------------------
// MFMA fp16 GEMM device body (round-6 proven structure): 128x128 tile, BK=64,
// 4 waves, single 32KB LDS, stage->barrier->compute->barrier, T2 swizzle,
// T1 bijective XCD swizzle. Output modes (per-block-uniform runtime select):
// kout!=0 -> K f16 / V fp32 split; Cb!=0 -> f16; else Cf fp32 (+bias).
// LESSON (round 8): this body must be inlined at exactly ONE call site per
// kernel -- two inlined copies doubled VGPR (84->168) and halved occupancy.
// ---------------------------------------------------------------------------
__device__ inline void async_copy16(const void* gptr, void* lptr) {
    __builtin_amdgcn_global_load_lds(
        (const __attribute__((address_space(1))) unsigned*)gptr,
        (__attribute__((address_space(3))) unsigned*)lptr, 16, 0, 0);
}

__device__ inline void gemm_body(
    const _Float16* __restrict__ A, const _Float16* __restrict__ B,
    float* __restrict__ Cf, _Float16* __restrict__ Cb,
    _Float16* __restrict__ kout, float* __restrict__ vout,
    int Mreal, int N, int KK, int ntn, const float* __restrict__ bias,
    int bid, int nwg, _Float16* As, _Float16* Bs)
{
    const int t = threadIdx.x;
    const int wave = t >> 6, lane = t & 63;
    const int lr = lane & 15, lg = lane >> 4;
    const int wr = wave >> 1, wc = wave & 1;

    // T1 bijective XCD-chunk swizzle (m204)
    const int q = nwg >> 3, r = nwg & 7;
    const int xcd = bid & 7, idx = bid >> 3;
    const int swz = (xcd < r ? xcd * (q + 1) : r * (q + 1) + (xcd - r) * q) + idx;
    const int m0 = (swz / ntn) * 128, n0 = (swz % ntn) * 128;

    f32x4 acc[4][4] = {};

    const int sr = lane >> 3;                   // row within staging instr
    const int sk = 8 * ((lane & 7) ^ sr);       // T2 pre-swizzled k-elem offset

    for (int k0 = 0; k0 < KK; k0 += 64) {
        __syncthreads();   // previous compute done
#pragma unroll
        for (int s = 0; s < 4; ++s) {
            const int ti = wave * 4 + s;
            const int row = ti * 8 + sr;
            async_copy16(A + (size_t)(m0 + row) * KK + k0 + sk, As + ti * 512);
            async_copy16(B + (size_t)(n0 + row) * KK + k0 + sk, Bs + ti * 512);
        }
        __syncthreads();   // staging complete (barrier drains vmcnt)

        f16x8 af[4][2], bf_[4][2];
#pragma unroll
        for (int i = 0; i < 4; ++i)
#pragma unroll
            for (int ki = 0; ki < 2; ++ki) {
                const int koff = (ki * 32 + lg * 8) ^ ((lr & 7) * 8);
                af[i][ki]  = *(const f16x8*)(As + (wr * 64 + i * 16 + lr) * 64 + koff);
                bf_[i][ki] = *(const f16x8*)(Bs + (wc * 64 + i * 16 + lr) * 64 + koff);
            }
#pragma unroll
        for (int ki = 0; ki < 2; ++ki)
#pragma unroll
            for (int i = 0; i < 4; ++i)
#pragma unroll
                for (int j = 0; j < 4; ++j)
                    acc[i][j] = __builtin_amdgcn_mfma_f32_16x16x32_f16(
                        af[i][ki], bf_[j][ki], acc[i][j], 0, 0, 0);
    }

    // epilogue: C row = lg*4 + rr, col = lr within fragment (m89 layout)
#pragma unroll
    for (int i = 0; i < 4; ++i) {
#pragma unroll
        for (int j = 0; j < 4; ++j) {
            const int col = n0 + wc * 64 + j * 16 + lr;
            const float bv = bias ? bias[col] : 0.f;
#pragma unroll
            for (int rr = 0; rr < 4; ++rr) {
                const int row = m0 + wr * 64 + i * 16 + lg * 4 + rr;
                const float v = acc[i][j][rr] + bv;
                if (kout) {
                    if (row < Mreal) {
                        if (col < D_MODEL) kout[(size_t)row * D_MODEL + col] = (_Float16)v;
                        else               vout[(size_t)row * D_MODEL + col - D_MODEL] = v;
                    }
                } else if (Cb) {
                    Cb[(size_t)row * N + col] = (_Float16)v;
                } else {
                    Cf[(size_t)row * N + col] = v;
                }
            }
        }
    }
}

// Mega-GEMM: Q projection (640 blocks) + fused K|V projection (100 blocks),
// ONE gemm_body call site; operands selected per-block-uniformly beforehand.
#define GQ_BLOCKS  ((MQ/128)*(D_MODEL/128))            // 640
#define GKV_BLOCKS ((MKV_PAD/128)*(2*D_MODEL/128))     // 100

__global__ __launch_bounds__(256) void gemm_qkv(
    const _Float16* __restrict__ hidf, const _Float16* __restrict__ B2Tq,
    _Float16* __restrict__ qf,
    const _Float16* __restrict__ encb, const _Float16* __restrict__ B2Tkv,
    _Float16* __restrict__ kf, float* __restrict__ vbuf)
{
    __shared__ __align__(16) _Float16 As[128 * 64];
    __shared__ __align__(16) _Float16 Bs[128 * 64];
    const bool isQ = blockIdx.x < GQ_BLOCKS;
    const _Float16* A    = isQ ? hidf : encb;
    const _Float16* B    = isQ ? B2Tq : B2Tkv;
    _Float16* Cb         = isQ ? qf : nullptr;
    _Float16* kout       = isQ ? nullptr : kf;
    float*    vout       = isQ ? nullptr : vbuf;
    const int Mreal      = isQ ? MQ : MKV;
    const int N          = isQ ? D_MODEL : 2 * D_MODEL;
    const int KK         = isQ ? D_MODEL : DX;
    const int ntn        = isQ ? D_MODEL / 128 : 2 * D_MODEL / 128;
    const int bid        = isQ ? blockIdx.x : blockIdx.x - GQ_BLOCKS;
    const int nwg        = isQ ? GQ_BLOCKS : GKV_BLOCKS;
    gemm_body(A, B, nullptr, Cb, kout, vout, Mreal, N, KK, ntn, nullptr,
              bid, nwg, As, Bs);
}

__global__ __launch_bounds__(256) void gemm_out(
    const _Float16* __restrict__ hsf, const _Float16* __restrict__ B2To,
    float* __restrict__ out, const float* __restrict__ bo)
{
    __shared__ __align__(16) _Float16 As[128 * 64];
    __shared__ __align__(16) _Float16 Bs[128 * 64];
    gemm_body(hsf, B2To, out, nullptr, nullptr, nullptr,
              MQ, D_MODEL, D_MODEL, D_MODEL / 128, bo,
              blockIdx.x, GQ_BLOCKS, As, Bs);
}

// ---------------------------------------------------------------------------
// Ortho-decomp retain transform: reads fp32 V, writes f16 V.
// ---------------------------------------------------------------------------
__global__ __launch_bounds__(256) void retain_kernel(
    const float* __restrict__ vbuf, _Float16* __restrict__ vf16,
    const float* __restrict__ tv)
{
    const int l = blockIdx.x % LTXT;
    const int r = blockIdx.x / LTXT;
    const int t = threadIdx.x;

    float g00=0,g01=0,g02=0,g11=0,g12=0,g22=0,tp0=0,tp1=0,tp2=0,pp=0;
    float p_save[10], t0s[10], t1s[10], t2s[10];
#pragma unroll
    for (int it = 0; it < 10; ++it) {
        const int j   = t + it * 256;
        const int m16 = j / HD, d = j % HD;
        const int e = m16 >> 3, h = m16 & 7;
        const float T0 = tv[((size_t)(e*24 +  0 + h) * LTXT + l) * HD + d];
        const float T1 = tv[((size_t)(e*24 +  8 + h) * LTXT + l) * HD + d];
        const float T2 = tv[((size_t)(e*24 + 16 + h) * LTXT + l) * HD + d];
        const float p  = vbuf[((size_t)((e*4 + r) * LTXT + l)) * D_MODEL + h*HD + d];
        p_save[it] = p; t0s[it] = T0; t1s[it] = T1; t2s[it] = T2;
        g00 += T0*T0; g01 += T0*T1; g02 += T0*T2;
        g11 += T1*T1; g12 += T1*T2; g22 += T2*T2;
        tp0 += T0*p;  tp1 += T1*p;  tp2 += T2*p;  pp += p*p;
    }

    __shared__ float part[4][10];
    const int wave = t >> 6, lane = t & 63;
    float vals[10] = {g00,g01,g02,g11,g12,g22,tp0,tp1,tp2,pp};
#pragma unroll
    for (int i = 0; i < 10; ++i) {
        float x = vals[i];
        x += __shfl_down(x, 32); x += __shfl_down(x, 16);
        x += __shfl_down(x,  8); x += __shfl_down(x,  4);
        x += __shfl_down(x,  2); x += __shfl_down(x,  1);
        if (lane == 0) part[wave][i] = x;
    }
    __syncthreads();

    float s[10];
#pragma unroll
    for (int i = 0; i < 10; ++i)
        s[i] = part[0][i] + part[1][i] + part[2][i] + part[3][i];

    const float G[3][3] = {{s[0],s[1],s[2]},{s[1],s[3],s[4]},{s[2],s[4],s[5]}};
    const float tp[3] = {s[6], s[7], s[8]};
    const float ppv = s[9];

    float Pm[3][3];
#pragma unroll
    for (int c = 0; c < 3; ++c)
#pragma unroll
        for (int e = 0; e < 3; ++e) {
            float v = (c == e) ? 1.f : 0.f;
            if (c > e) v -= G[c][e] / G[e][e];
            Pm[c][e] = v;
        }

    const float nP = fmaxf(sqrtf(ppv), 1e-8f);
    float w[3], cosg[3];
#pragma unroll
    for (int c = 0; c < 3; ++c) {
        const float nT = fmaxf(sqrtf(G[c][c]), 1e-8f);
        const float cosv = tp[c] / (nT * nP);
        cosg[c] = 1.f / (1.f + expf(-10.f * (cosv - 0.5f)));
        float d1 = Pm[c][0]*tp[0] + Pm[c][1]*tp[1] + Pm[c][2]*tp[2];
        float d2 = 0.f;
#pragma unroll
        for (int e = 0; e < 3; ++e)
#pragma unroll
            for (int f = 0; f < 3; ++f) d2 += Pm[c][e] * Pm[c][f] * G[e][f];
        float wc = d1 / d2;
        if (isnan(wc)) wc = 0.f;
        if (l == 0)    wc = 0.f;
        w[c] = wc;
    }

    float coef[3];
#pragma unroll
    for (int e = 0; e < 3; ++e)
        coef[e] = cosg[e] * (w[0]*Pm[0][e] + w[1]*Pm[1][e] + w[2]*Pm[2][e]);

#pragma unroll
    for (int it = 0; it < 10; ++it) {
        const int j   = t + it * 256;
        const int m16 = j / HD, d = j % HD;
        const int e = m16 >> 3, h = m16 & 7;
        const float era = coef[0]*t0s[it] + coef[1]*t1s[it] + coef[2]*t2s[it];
        vf16[((size_t)((e*4 + r) * LTXT + l)) * D_MODEL + h*HD + d] =
            (_Float16)(p_save[it] - era);
    }
}

// ---------------------------------------------------------------------------
// MFMA attention (round-3 structure, f16 K/V inputs).
// ---------------------------------------------------------------------------
#define KSTRIDE 168
#define VSTRIDE 104
#define PSTRIDE 104

__global__ __launch_bounds__(256, 3) void attn_mfma(
    const _Float16* __restrict__ qb,     // [8192][1280] f16
    const _Float16* __restrict__ kf,     // [616][1280] f16
    const _Float16* __restrict__ vf,     // [616][1280] f16 (retained)
    _Float16* __restrict__ hs)           // [8192][1280] f16 out
{
    __shared__ _Float16 KV[160 * VSTRIDE];    // K view: [80][KSTRIDE]
    __shared__ _Float16 Ps[4][16 * PSTRIDE];
    const int bh = blockIdx.x, b = bh >> 3, h = bh & 7;
    const int qt = blockIdx.y;
    const int t = threadIdx.x, wave = t >> 6, lane = t & 63;
    const int lr = lane & 15, lg = lane >> 4;

    // stage K as [80][KSTRIDE] f16, rows >=77 zeroed
    for (int c = t; c < 1600; c += 256) {
        const int l = c / 20, d8 = (c % 20) * 8;
        f16x8 u;
#pragma unroll
        for (int i = 0; i < 8; ++i) u[i] = (_Float16)0.f;
        if (l < LTXT) u = *(const f16x8*)&kf[((size_t)(b * LTXT + l)) * D_MODEL + h * HD + d8];
        *(f16x8*)&KV[l * KSTRIDE + d8] = u;
    }
    {
        for (int i = lane; i < 256; i += 64)
            Ps[wave][(i >> 4) * PSTRIDE + 80 + (i & 15)] = (_Float16)0.f;
    }
    __syncthreads();

    const int qrow0 = b * S_LEN + qt * 64 + wave * 16;
    const _Float16* qp = qb + (size_t)(qrow0 + lr) * D_MODEL + h * HD;
    f16x8 af[5];
#pragma unroll
    for (int kt = 0; kt < 5; ++kt)
        af[kt] = *(const f16x8*)&qp[kt * 32 + lg * 8];

    f32x4 accs[5] = {};
#pragma unroll
    for (int j = 0; j < 5; ++j)
#pragma unroll
        for (int kt = 0; kt < 5; ++kt) {
            const f16x8 bf = *(const f16x8*)&KV[(j * 16 + lr) * KSTRIDE + kt * 32 + lg * 8];
            accs[j] = __builtin_amdgcn_mfma_f32_16x16x32_f16(af[kt], bf, accs[j], 0, 0, 0);
        }

    float s[5][4];
    const float scale = 0.07905694150420949f;  // 1/sqrt(160)
#pragma unroll
    for (int j = 0; j < 5; ++j)
#pragma unroll
        for (int r = 0; r < 4; ++r)
            s[j][r] = accs[j][r] * scale;
    if (lr >= 13) { s[4][0] = -1e30f; s[4][1] = -1e30f; s[4][2] = -1e30f; s[4][3] = -1e30f; }

    float rsum[4];
#pragma unroll
    for (int r = 0; r < 4; ++r) {
        float m = s[0][r];
#pragma unroll
        for (int j = 1; j < 5; ++j) m = fmaxf(m, s[j][r]);
        m = fmaxf(m, __shfl_xor(m, 1));
        m = fmaxf(m, __shfl_xor(m, 2));
        m = fmaxf(m, __shfl_xor(m, 4));
        m = fmaxf(m, __shfl_xor(m, 8));
        float sum = 0.f;
#pragma unroll
        for (int j = 0; j < 5; ++j) {
            const float p = __expf(s[j][r] - m);
            s[j][r] = p;
            sum += p;
        }
        sum += __shfl_xor(sum, 1);
        sum += __shfl_xor(sum, 2);
        sum += __shfl_xor(sum, 4);
        sum += __shfl_xor(sum, 8);
        rsum[r] = sum;
    }

#pragma unroll
    for (int j = 0; j < 5; ++j)
#pragma unroll
        for (int r = 0; r < 4; ++r)
            Ps[wave][(lg * 4 + r) * PSTRIDE + j * 16 + lr] = (_Float16)s[j][r];

    __syncthreads();   // all waves done reading K view of KV

    // stage V^T as [160][VSTRIDE] f16, key cols >=77 zeroed
    for (int c = t; c < 1920; c += 256) {
        const int l = c / 20, d8 = (c % 20) * 8;
        f16x8 vv;
#pragma unroll
        for (int i = 0; i < 8; ++i) vv[i] = (_Float16)0.f;
        if (l < LTXT) vv = *(const f16x8*)&vf[((size_t)(b * LTXT + l)) * D_MODEL + h * HD + d8];
#pragma unroll
        for (int i = 0; i < 8; ++i)
            KV[(d8 + i) * VSTRIDE + l] = vv[i];
    }
    __syncthreads();

    f16x8 pa[3];
#pragma unroll
    for (int kt = 0; kt < 3; ++kt)
        pa[kt] = *(const f16x8*)&Ps[wave][lr * PSTRIDE + kt * 32 + lg * 8];
    f32x4 acch[10] = {};
#pragma unroll
    for (int dt = 0; dt < 10; ++dt)
#pragma unroll
        for (int kt = 0; kt < 3; ++kt) {
            const f16x8 vb = *(const f16x8*)&KV[(dt * 16 + lr) * VSTRIDE + kt * 32 + lg * 8];
            acch[dt] = __builtin_amdgcn_mfma_f32_16x16x32_f16(pa[kt], vb, acch[dt], 0, 0, 0);
        }

    const float inv[4] = {1.f / rsum[0], 1.f / rsum[1], 1.f / rsum[2], 1.f / rsum[3]};
#pragma unroll
    for (int dt = 0; dt < 10; ++dt) {
        const int col = h * HD + dt * 16 + lr;
#pragma unroll
        for (int r = 0; r < 4; ++r) {
            const int row = qrow0 + lg * 4 + r;
            hs[(size_t)row * D_MODEL + col] = (_Float16)(acch[dt][r] * inv[r]);
        }
    }
}

// ---------------------------------------------------------------------------
extern "C" void kernel_launch(void* const* d_in, const int* in_sizes, int n_in,
                              void* d_out, int out_size, void* d_ws, size_t ws_size,
                              hipStream_t stream)
{
    const float* hidden = (const float*)d_in[0]; // [8,1024,1280]
    const float* enc    = (const float*)d_in[1]; // [8,77,768]
    const float* Wq     = (const float*)d_in[2]; // [1280,1280]
    const float* Wk     = (const float*)d_in[3]; // [768,1280]
    const float* Wv     = (const float*)d_in[4]; // [768,1280]
    const float* Wo     = (const float*)d_in[5]; // [1280,1280]
    const float* bo     = (const float*)d_in[6]; // [1280]
    const float* tv     = (const float*)d_in[7]; // [48,77,160]
    float* out = (float*)d_out;

    // ws layout (~81 MB, all 16B-aligned boundaries)
    _Float16* kf     = (_Float16*)d_ws;                        // [616,1280] f16 K
    float*    vbuf   = (float*)(kf + (size_t)MKV * D_MODEL);   // [616,1280] f32 V (pre-retain)
    _Float16* vf16   = (_Float16*)(vbuf + (size_t)MKV * D_MODEL); // [616,1280] f16 V (retained)
    _Float16* qf     = vf16 + (size_t)MKV * D_MODEL;           // [8192,1280]
    _Float16* hsf    = qf   + (size_t)MQ * D_MODEL;            // [8192,1280]
    _Float16* hidf   = hsf  + (size_t)MQ * D_MODEL;            // [8192,1280]
    _Float16* encb   = hidf + (size_t)MQ * D_MODEL;            // [640,768]
    _Float16* B2Tq   = encb + (size_t)MKV_PAD * DX;            // [1280,1280]
    _Float16* B2To   = B2Tq + (size_t)D_MODEL * D_MODEL;       // [1280,1280]
    _Float16* B2Tkv  = B2To + (size_t)D_MODEL * D_MODEL;       // [2560,768]

    // 1. all input conversions/transposes in one launch
    prep_kernel<<<NB_PREP, 256, 0, stream>>>(
        hidden, enc, Wq, Wk, Wv, Wo, hidf, encb, B2Tq, B2To, B2Tkv);

    // 2. Q projection + fused K|V projection, single gemm_body call site
    gemm_qkv<<<GQ_BLOCKS + GKV_BLOCKS, 256, 0, stream>>>(
        hidf, B2Tq, qf, encb, B2Tkv, kf, vbuf);

    // 3. concept-erasure retain transform: fp32 V -> f16 V
    retain_kernel<<<4 * LTXT, 256, 0, stream>>>(vbuf, vf16, tv);

    // 4. MFMA attention (f16 K/V): writes hs f16
    attn_mfma<<<dim3(NBH, S_LEN / 64), 256, 0, stream>>>(qf, kf, vf16, hsf);

    // 5. out = hs @ Wo + bo
    gemm_out<<<GQ_BLOCKS, 256, 0, stream>>>(hsf, B2To, out, bo);
}

// Round 10
// 182.101 us; speedup vs baseline: 1.1686x; 1.1657x over previous
//
#include <hip/hip_runtime.h>
#include <hip/hip_bf16.h>
#include <math.h>

// Problem constants
#define BATCH   8
#define S_LEN   1024
#define D_MODEL 1280
#define DX      768
#define NH      8
#define HD      160
#define LTXT    77
#define NBH     (BATCH*NH)      // 64
#define MKV_PAD 640             // 616 padded to 128-multiple
#define MQ      (BATCH*S_LEN)   // 8192
#define MKV     (BATCH*LTXT)    // 616

typedef _Float16 f16x8 __attribute__((ext_vector_type(8)));
typedef _Float16 f16x4 __attribute__((ext_vector_type(4)));
typedef float    f32x4 __attribute__((ext_vector_type(4)));

// ---------------------------------------------------------------------------
// Fused prep kernel: all input-only conversions in ONE launch.
// ---------------------------------------------------------------------------
#define NB_HID 10240   // 8192*1280/4/256
#define NB_ENC 480     // 640*768/4/256
#define NB_WQ  1600    // 40x40 32x32-tiles
#define NB_WO  1600
#define NB_WK  960     // 24x40
#define NB_WV  960
#define NB_PREP (NB_HID+NB_ENC+NB_WQ+NB_WO+NB_WK+NB_WV)

__device__ inline void to_f16_dev(const float* __restrict__ X,
                                  _Float16* __restrict__ Y,
                                  int K, int Mreal, int bid)
{
    const size_t g = ((size_t)bid * 256 + threadIdx.x) * 4;
    const int row = (int)(g / K);
    float4 x = make_float4(0.f, 0.f, 0.f, 0.f);
    if (row < Mreal) x = *(const float4*)&X[g];
    f16x4 o;
    o[0] = (_Float16)x.x; o[1] = (_Float16)x.y;
    o[2] = (_Float16)x.z; o[3] = (_Float16)x.w;
    *(f16x4*)&Y[g] = o;
}

__device__ inline void wt_t_dev(const float* __restrict__ W,
                                _Float16* __restrict__ BT,
                                int K, int N, int KLD, int noff,
                                int bx, int by, float (*tile)[33])
{
    const int k0 = by * 32, n0 = bx * 32;
    const int tx = threadIdx.x & 31, ty = threadIdx.x >> 5;
#pragma unroll
    for (int r = 0; r < 32; r += 8)
        tile[r + ty][tx] = W[(size_t)(k0 + r + ty) * N + n0 + tx];
    __syncthreads();
#pragma unroll
    for (int r = 0; r < 32; r += 8) {
        const int n = noff + n0 + r + ty, k = k0 + tx;
        BT[(size_t)n * KLD + k] = (_Float16)tile[tx][r + ty];
    }
}

__global__ __launch_bounds__(256) void prep_kernel(
    const float* __restrict__ hidden, const float* __restrict__ enc,
    const float* __restrict__ Wq, const float* __restrict__ Wk,
    const float* __restrict__ Wv, const float* __restrict__ Wo,
    _Float16* __restrict__ hidf, _Float16* __restrict__ encb,
    _Float16* __restrict__ B2Tq, _Float16* __restrict__ B2To,
    _Float16* __restrict__ B2Tkv)
{
    __shared__ float tile[32][33];
    int bid = blockIdx.x;
    if (bid < NB_HID) { to_f16_dev(hidden, hidf, D_MODEL, MQ, bid); return; }
    bid -= NB_HID;
    if (bid < NB_ENC) { to_f16_dev(enc, encb, DX, MKV, bid); return; }
    bid -= NB_ENC;
    if (bid < NB_WQ)  { wt_t_dev(Wq, B2Tq, D_MODEL, D_MODEL, D_MODEL, 0, bid % 40, bid / 40, tile); return; }
    bid -= NB_WQ;
    if (bid < NB_WO)  { wt_t_dev(Wo, B2To, D_MODEL, D_MODEL, D_MODEL, 0, bid % 40, bid / 40, tile); return; }
    bid -= NB_WO;
    if (bid < NB_WK)  { wt_t_dev(Wk, B2Tkv, DX, D_MODEL, DX, 0, bid % 40, bid / 40, tile); return; }
    bid -= NB_WK;
    wt_t_dev(Wv, B2Tkv, DX, D_MODEL, DX, D_MODEL, bid % 40, bid / 40, tile);
}

// ---------------------------------------------------------------------------
// MFMA fp16 GEMM device body (round-6 proven structure): 128x128 tile, BK=64,
// 4 waves, single 32KB LDS, stage->barrier->compute->barrier, T2 swizzle,
// T1 bijective XCD swizzle.
// MODE is a TEMPLATE param so each __global__ wrapper gets exactly one
// specialized epilogue (round-8/9 LESSON: runtime mode select / multiple
// inlined call sites -> VGPR 84->168, occupancy halved, 2x slowdown).
//   MODE 0: fp32 store + bias (out-GEMM)
//   MODE 1: f16 store (Q-GEMM)
//   MODE 2: col<1280 -> f16 K, col>=1280 -> fp32 V, rows guarded (KV-GEMM)
// ---------------------------------------------------------------------------
__device__ inline void async_copy16(const void* gptr, void* lptr) {
    __builtin_amdgcn_global_load_lds(
        (const __attribute__((address_space(1))) unsigned*)gptr,
        (__attribute__((address_space(3))) unsigned*)lptr, 16, 0, 0);
}

template<int MODE>
__device__ inline void gemm_body(
    const _Float16* __restrict__ A, const _Float16* __restrict__ B,
    void* __restrict__ C0, float* __restrict__ vout,
    int Mreal, int N, int KK, int ntn, const float* __restrict__ bias,
    int bid, int nwg, _Float16* As, _Float16* Bs)
{
    const int t = threadIdx.x;
    const int wave = t >> 6, lane = t & 63;
    const int lr = lane & 15, lg = lane >> 4;
    const int wr = wave >> 1, wc = wave & 1;

    // T1 bijective XCD-chunk swizzle (m204)
    const int q = nwg >> 3, r = nwg & 7;
    const int xcd = bid & 7, idx = bid >> 3;
    const int swz = (xcd < r ? xcd * (q + 1) : r * (q + 1) + (xcd - r) * q) + idx;
    const int m0 = (swz / ntn) * 128, n0 = (swz % ntn) * 128;

    f32x4 acc[4][4] = {};

    const int sr = lane >> 3;                   // row within staging instr
    const int sk = 8 * ((lane & 7) ^ sr);       // T2 pre-swizzled k-elem offset

    for (int k0 = 0; k0 < KK; k0 += 64) {
        __syncthreads();   // previous compute done
#pragma unroll
        for (int s = 0; s < 4; ++s) {
            const int ti = wave * 4 + s;
            const int row = ti * 8 + sr;
            async_copy16(A + (size_t)(m0 + row) * KK + k0 + sk, As + ti * 512);
            async_copy16(B + (size_t)(n0 + row) * KK + k0 + sk, Bs + ti * 512);
        }
        __syncthreads();   // staging complete (barrier drains vmcnt)

        f16x8 af[4][2], bf_[4][2];
#pragma unroll
        for (int i = 0; i < 4; ++i)
#pragma unroll
            for (int ki = 0; ki < 2; ++ki) {
                const int koff = (ki * 32 + lg * 8) ^ ((lr & 7) * 8);
                af[i][ki]  = *(const f16x8*)(As + (wr * 64 + i * 16 + lr) * 64 + koff);
                bf_[i][ki] = *(const f16x8*)(Bs + (wc * 64 + i * 16 + lr) * 64 + koff);
            }
#pragma unroll
        for (int ki = 0; ki < 2; ++ki)
#pragma unroll
            for (int i = 0; i < 4; ++i)
#pragma unroll
                for (int j = 0; j < 4; ++j)
                    acc[i][j] = __builtin_amdgcn_mfma_f32_16x16x32_f16(
                        af[i][ki], bf_[j][ki], acc[i][j], 0, 0, 0);
    }

    // epilogue: C row = lg*4 + rr, col = lr within fragment (m89 layout)
#pragma unroll
    for (int i = 0; i < 4; ++i) {
#pragma unroll
        for (int j = 0; j < 4; ++j) {
            const int col = n0 + wc * 64 + j * 16 + lr;
            const float bv = (MODE == 0 && bias) ? bias[col] : 0.f;
#pragma unroll
            for (int rr = 0; rr < 4; ++rr) {
                const int row = m0 + wr * 64 + i * 16 + lg * 4 + rr;
                const float v = acc[i][j][rr] + bv;
                if (MODE == 0) {
                    ((float*)C0)[(size_t)row * N + col] = v;
                } else if (MODE == 1) {
                    ((_Float16*)C0)[(size_t)row * N + col] = (_Float16)v;
                } else {
                    if (row < Mreal) {
                        if (col < D_MODEL)
                            ((_Float16*)C0)[(size_t)row * D_MODEL + col] = (_Float16)v;
                        else
                            vout[(size_t)row * D_MODEL + col - D_MODEL] = v;
                    }
                }
            }
        }
    }
}

#define GQ_BLOCKS  ((MQ/128)*(D_MODEL/128))            // 640
#define GKV_BLOCKS ((MKV_PAD/128)*(2*D_MODEL/128))     // 100

__global__ __launch_bounds__(256) void gemm_q(
    const _Float16* __restrict__ hidf, const _Float16* __restrict__ B2Tq,
    _Float16* __restrict__ qf)
{
    __shared__ __align__(16) _Float16 As[128 * 64];
    __shared__ __align__(16) _Float16 Bs[128 * 64];
    gemm_body<1>(hidf, B2Tq, qf, nullptr, MQ, D_MODEL, D_MODEL,
                 D_MODEL / 128, nullptr, blockIdx.x, GQ_BLOCKS, As, Bs);
}

__global__ __launch_bounds__(256) void gemm_kv(
    const _Float16* __restrict__ encb, const _Float16* __restrict__ B2Tkv,
    _Float16* __restrict__ kf, float* __restrict__ vbuf)
{
    __shared__ __align__(16) _Float16 As[128 * 64];
    __shared__ __align__(16) _Float16 Bs[128 * 64];
    gemm_body<2>(encb, B2Tkv, kf, vbuf, MKV, 2 * D_MODEL, DX,
                 2 * D_MODEL / 128, nullptr, blockIdx.x, GKV_BLOCKS, As, Bs);
}

__global__ __launch_bounds__(256) void gemm_out(
    const _Float16* __restrict__ hsf, const _Float16* __restrict__ B2To,
    float* __restrict__ out, const float* __restrict__ bo)
{
    __shared__ __align__(16) _Float16 As[128 * 64];
    __shared__ __align__(16) _Float16 Bs[128 * 64];
    gemm_body<0>(hsf, B2To, out, nullptr, MQ, D_MODEL, D_MODEL,
                 D_MODEL / 128, bo, blockIdx.x, GQ_BLOCKS, As, Bs);
}

// ---------------------------------------------------------------------------
// Ortho-decomp retain transform: reads fp32 V, writes f16 V.
// ---------------------------------------------------------------------------
__global__ __launch_bounds__(256) void retain_kernel(
    const float* __restrict__ vbuf, _Float16* __restrict__ vf16,
    const float* __restrict__ tv)
{
    const int l = blockIdx.x % LTXT;
    const int r = blockIdx.x / LTXT;
    const int t = threadIdx.x;

    float g00=0,g01=0,g02=0,g11=0,g12=0,g22=0,tp0=0,tp1=0,tp2=0,pp=0;
    float p_save[10], t0s[10], t1s[10], t2s[10];
#pragma unroll
    for (int it = 0; it < 10; ++it) {
        const int j   = t + it * 256;
        const int m16 = j / HD, d = j % HD;
        const int e = m16 >> 3, h = m16 & 7;
        const float T0 = tv[((size_t)(e*24 +  0 + h) * LTXT + l) * HD + d];
        const float T1 = tv[((size_t)(e*24 +  8 + h) * LTXT + l) * HD + d];
        const float T2 = tv[((size_t)(e*24 + 16 + h) * LTXT + l) * HD + d];
        const float p  = vbuf[((size_t)((e*4 + r) * LTXT + l)) * D_MODEL + h*HD + d];
        p_save[it] = p; t0s[it] = T0; t1s[it] = T1; t2s[it] = T2;
        g00 += T0*T0; g01 += T0*T1; g02 += T0*T2;
        g11 += T1*T1; g12 += T1*T2; g22 += T2*T2;
        tp0 += T0*p;  tp1 += T1*p;  tp2 += T2*p;  pp += p*p;
    }

    __shared__ float part[4][10];
    const int wave = t >> 6, lane = t & 63;
    float vals[10] = {g00,g01,g02,g11,g12,g22,tp0,tp1,tp2,pp};
#pragma unroll
    for (int i = 0; i < 10; ++i) {
        float x = vals[i];
        x += __shfl_down(x, 32); x += __shfl_down(x, 16);
        x += __shfl_down(x,  8); x += __shfl_down(x,  4);
        x += __shfl_down(x,  2); x += __shfl_down(x,  1);
        if (lane == 0) part[wave][i] = x;
    }
    __syncthreads();

    float s[10];
#pragma unroll
    for (int i = 0; i < 10; ++i)
        s[i] = part[0][i] + part[1][i] + part[2][i] + part[3][i];

    const float G[3][3] = {{s[0],s[1],s[2]},{s[1],s[3],s[4]},{s[2],s[4],s[5]}};
    const float tp[3] = {s[6], s[7], s[8]};
    const float ppv = s[9];

    float Pm[3][3];
#pragma unroll
    for (int c = 0; c < 3; ++c)
#pragma unroll
        for (int e = 0; e < 3; ++e) {
            float v = (c == e) ? 1.f : 0.f;
            if (c > e) v -= G[c][e] / G[e][e];
            Pm[c][e] = v;
        }

    const float nP = fmaxf(sqrtf(ppv), 1e-8f);
    float w[3], cosg[3];
#pragma unroll
    for (int c = 0; c < 3; ++c) {
        const float nT = fmaxf(sqrtf(G[c][c]), 1e-8f);
        const float cosv = tp[c] / (nT * nP);
        cosg[c] = 1.f / (1.f + expf(-10.f * (cosv - 0.5f)));
        float d1 = Pm[c][0]*tp[0] + Pm[c][1]*tp[1] + Pm[c][2]*tp[2];
        float d2 = 0.f;
#pragma unroll
        for (int e = 0; e < 3; ++e)
#pragma unroll
            for (int f = 0; f < 3; ++f) d2 += Pm[c][e] * Pm[c][f] * G[e][f];
        float wc = d1 / d2;
        if (isnan(wc)) wc = 0.f;
        if (l == 0)    wc = 0.f;
        w[c] = wc;
    }

    float coef[3];
#pragma unroll
    for (int e = 0; e < 3; ++e)
        coef[e] = cosg[e] * (w[0]*Pm[0][e] + w[1]*Pm[1][e] + w[2]*Pm[2][e]);

#pragma unroll
    for (int it = 0; it < 10; ++it) {
        const int j   = t + it * 256;
        const int m16 = j / HD, d = j % HD;
        const int e = m16 >> 3, h = m16 & 7;
        const float era = coef[0]*t0s[it] + coef[1]*t1s[it] + coef[2]*t2s[it];
        vf16[((size_t)((e*4 + r) * LTXT + l)) * D_MODEL + h*HD + d] =
            (_Float16)(p_save[it] - era);
    }
}

// ---------------------------------------------------------------------------
// MFMA attention (round-3 structure, f16 K/V inputs).
// ---------------------------------------------------------------------------
#define KSTRIDE 168
#define VSTRIDE 104
#define PSTRIDE 104

__global__ __launch_bounds__(256, 3) void attn_mfma(
    const _Float16* __restrict__ qb,     // [8192][1280] f16
    const _Float16* __restrict__ kf,     // [616][1280] f16
    const _Float16* __restrict__ vf,     // [616][1280] f16 (retained)
    _Float16* __restrict__ hs)           // [8192][1280] f16 out
{
    __shared__ _Float16 KV[160 * VSTRIDE];    // K view: [80][KSTRIDE]
    __shared__ _Float16 Ps[4][16 * PSTRIDE];
    const int bh = blockIdx.x, b = bh >> 3, h = bh & 7;
    const int qt = blockIdx.y;
    const int t = threadIdx.x, wave = t >> 6, lane = t & 63;
    const int lr = lane & 15, lg = lane >> 4;

    // stage K as [80][KSTRIDE] f16, rows >=77 zeroed
    for (int c = t; c < 1600; c += 256) {
        const int l = c / 20, d8 = (c % 20) * 8;
        f16x8 u;
#pragma unroll
        for (int i = 0; i < 8; ++i) u[i] = (_Float16)0.f;
        if (l < LTXT) u = *(const f16x8*)&kf[((size_t)(b * LTXT + l)) * D_MODEL + h * HD + d8];
        *(f16x8*)&KV[l * KSTRIDE + d8] = u;
    }
    {
        for (int i = lane; i < 256; i += 64)
            Ps[wave][(i >> 4) * PSTRIDE + 80 + (i & 15)] = (_Float16)0.f;
    }
    __syncthreads();

    const int qrow0 = b * S_LEN + qt * 64 + wave * 16;
    const _Float16* qp = qb + (size_t)(qrow0 + lr) * D_MODEL + h * HD;
    f16x8 af[5];
#pragma unroll
    for (int kt = 0; kt < 5; ++kt)
        af[kt] = *(const f16x8*)&qp[kt * 32 + lg * 8];

    f32x4 accs[5] = {};
#pragma unroll
    for (int j = 0; j < 5; ++j)
#pragma unroll
        for (int kt = 0; kt < 5; ++kt) {
            const f16x8 bf = *(const f16x8*)&KV[(j * 16 + lr) * KSTRIDE + kt * 32 + lg * 8];
            accs[j] = __builtin_amdgcn_mfma_f32_16x16x32_f16(af[kt], bf, accs[j], 0, 0, 0);
        }

    float s[5][4];
    const float scale = 0.07905694150420949f;  // 1/sqrt(160)
#pragma unroll
    for (int j = 0; j < 5; ++j)
#pragma unroll
        for (int r = 0; r < 4; ++r)
            s[j][r] = accs[j][r] * scale;
    if (lr >= 13) { s[4][0] = -1e30f; s[4][1] = -1e30f; s[4][2] = -1e30f; s[4][3] = -1e30f; }

    float rsum[4];
#pragma unroll
    for (int r = 0; r < 4; ++r) {
        float m = s[0][r];
#pragma unroll
        for (int j = 1; j < 5; ++j) m = fmaxf(m, s[j][r]);
        m = fmaxf(m, __shfl_xor(m, 1));
        m = fmaxf(m, __shfl_xor(m, 2));
        m = fmaxf(m, __shfl_xor(m, 4));
        m = fmaxf(m, __shfl_xor(m, 8));
        float sum = 0.f;
#pragma unroll
        for (int j = 0; j < 5; ++j) {
            const float p = __expf(s[j][r] - m);
            s[j][r] = p;
            sum += p;
        }
        sum += __shfl_xor(sum, 1);
        sum += __shfl_xor(sum, 2);
        sum += __shfl_xor(sum, 4);
        sum += __shfl_xor(sum, 8);
        rsum[r] = sum;
    }

#pragma unroll
    for (int j = 0; j < 5; ++j)
#pragma unroll
        for (int r = 0; r < 4; ++r)
            Ps[wave][(lg * 4 + r) * PSTRIDE + j * 16 + lr] = (_Float16)s[j][r];

    __syncthreads();   // all waves done reading K view of KV

    // stage V^T as [160][VSTRIDE] f16, key cols >=77 zeroed
    for (int c = t; c < 1920; c += 256) {
        const int l = c / 20, d8 = (c % 20) * 8;
        f16x8 vv;
#pragma unroll
        for (int i = 0; i < 8; ++i) vv[i] = (_Float16)0.f;
        if (l < LTXT) vv = *(const f16x8*)&vf[((size_t)(b * LTXT + l)) * D_MODEL + h * HD + d8];
#pragma unroll
        for (int i = 0; i < 8; ++i)
            KV[(d8 + i) * VSTRIDE + l] = vv[i];
    }
    __syncthreads();

    f16x8 pa[3];
#pragma unroll
    for (int kt = 0; kt < 3; ++kt)
        pa[kt] = *(const f16x8*)&Ps[wave][lr * PSTRIDE + kt * 32 + lg * 8];
    f32x4 acch[10] = {};
#pragma unroll
    for (int dt = 0; dt < 10; ++dt)
#pragma unroll
        for (int kt = 0; kt < 3; ++kt) {
            const f16x8 vb = *(const f16x8*)&KV[(dt * 16 + lr) * VSTRIDE + kt * 32 + lg * 8];
            acch[dt] = __builtin_amdgcn_mfma_f32_16x16x32_f16(pa[kt], vb, acch[dt], 0, 0, 0);
        }

    const float inv[4] = {1.f / rsum[0], 1.f / rsum[1], 1.f / rsum[2], 1.f / rsum[3]};
#pragma unroll
    for (int dt = 0; dt < 10; ++dt) {
        const int col = h * HD + dt * 16 + lr;
#pragma unroll
        for (int r = 0; r < 4; ++r) {
            const int row = qrow0 + lg * 4 + r;
            hs[(size_t)row * D_MODEL + col] = (_Float16)(acch[dt][r] * inv[r]);
        }
    }
}

// ---------------------------------------------------------------------------
extern "C" void kernel_launch(void* const* d_in, const int* in_sizes, int n_in,
                              void* d_out, int out_size, void* d_ws, size_t ws_size,
                              hipStream_t stream)
{
    const float* hidden = (const float*)d_in[0]; // [8,1024,1280]
    const float* enc    = (const float*)d_in[1]; // [8,77,768]
    const float* Wq     = (const float*)d_in[2]; // [1280,1280]
    const float* Wk     = (const float*)d_in[3]; // [768,1280]
    const float* Wv     = (const float*)d_in[4]; // [768,1280]
    const float* Wo     = (const float*)d_in[5]; // [1280,1280]
    const float* bo     = (const float*)d_in[6]; // [1280]
    const float* tv     = (const float*)d_in[7]; // [48,77,160]
    float* out = (float*)d_out;

    // ws layout (~81 MB, all 16B-aligned boundaries)
    _Float16* kf     = (_Float16*)d_ws;                        // [616,1280] f16 K
    float*    vbuf   = (float*)(kf + (size_t)MKV * D_MODEL);   // [616,1280] f32 V (pre-retain)
    _Float16* vf16   = (_Float16*)(vbuf + (size_t)MKV * D_MODEL); // [616,1280] f16 V (retained)
    _Float16* qf     = vf16 + (size_t)MKV * D_MODEL;           // [8192,1280]
    _Float16* hsf    = qf   + (size_t)MQ * D_MODEL;            // [8192,1280]
    _Float16* hidf   = hsf  + (size_t)MQ * D_MODEL;            // [8192,1280]
    _Float16* encb   = hidf + (size_t)MQ * D_MODEL;            // [640,768]
    _Float16* B2Tq   = encb + (size_t)MKV_PAD * DX;            // [1280,1280]
    _Float16* B2To   = B2Tq + (size_t)D_MODEL * D_MODEL;       // [1280,1280]
    _Float16* B2Tkv  = B2To + (size_t)D_MODEL * D_MODEL;       // [2560,768]

    // 1. all input conversions/transposes in one launch
    prep_kernel<<<NB_PREP, 256, 0, stream>>>(
        hidden, enc, Wq, Wk, Wv, Wo, hidf, encb, B2Tq, B2To, B2Tkv);

    // 2. Q projection (dedicated kernel, MODE 1)
    gemm_q<<<GQ_BLOCKS, 256, 0, stream>>>(hidf, B2Tq, qf);

    // 3. fused K|V projection (dedicated kernel, MODE 2)
    gemm_kv<<<GKV_BLOCKS, 256, 0, stream>>>(encb, B2Tkv, kf, vbuf);

    // 4. concept-erasure retain transform: fp32 V -> f16 V
    retain_kernel<<<4 * LTXT, 256, 0, stream>>>(vbuf, vf16, tv);

    // 5. MFMA attention (f16 K/V): writes hs f16
    attn_mfma<<<dim3(NBH, S_LEN / 64), 256, 0, stream>>>(qf, kf, vf16, hsf);

    // 6. out = hs @ Wo + bo
    gemm_out<<<GQ_BLOCKS, 256, 0, stream>>>(hsf, B2To, out, bo);
}

// Round 11
// 160.721 us; speedup vs baseline: 1.3240x; 1.1330x over previous
//
#include <hip/hip_runtime.h>
#include <hip/hip_bf16.h>
#include <math.h>

// Problem constants
#define BATCH   8
#define S_LEN   1024
#define D_MODEL 1280
#define DX      768
#define NH      8
#define HD      160
#define LTXT    77
#define NBH     (BATCH*NH)      // 64
#define MKV_PAD 640             // 616 padded to 128-multiple
#define MQ      (BATCH*S_LEN)   // 8192
#define MKV     (BATCH*LTXT)    // 616

typedef _Float16 f16x8 __attribute__((ext_vector_type(8)));
typedef _Float16 f16x4 __attribute__((ext_vector_type(4)));
typedef float    f32x4 __attribute__((ext_vector_type(4)));

// ---------------------------------------------------------------------------
// Fused prep kernel: all input-only conversions in ONE launch (proven r10).
// ---------------------------------------------------------------------------
#define NB_HID 10240   // 8192*1280/4/256
#define NB_ENC 480     // 640*768/4/256
#define NB_WQ  1600    // 40x40 32x32-tiles
#define NB_WO  1600
#define NB_WK  960     // 24x40
#define NB_WV  960
#define NB_PREP (NB_HID+NB_ENC+NB_WQ+NB_WO+NB_WK+NB_WV)

__device__ inline void to_f16_dev(const float* __restrict__ X,
                                  _Float16* __restrict__ Y,
                                  int K, int Mreal, int bid)
{
    const size_t g = ((size_t)bid * 256 + threadIdx.x) * 4;
    const int row = (int)(g / K);
    float4 x = make_float4(0.f, 0.f, 0.f, 0.f);
    if (row < Mreal) x = *(const float4*)&X[g];
    f16x4 o;
    o[0] = (_Float16)x.x; o[1] = (_Float16)x.y;
    o[2] = (_Float16)x.z; o[3] = (_Float16)x.w;
    *(f16x4*)&Y[g] = o;
}

__device__ inline void wt_t_dev(const float* __restrict__ W,
                                _Float16* __restrict__ BT,
                                int K, int N, int KLD, int noff,
                                int bx, int by, float (*tile)[33])
{
    const int k0 = by * 32, n0 = bx * 32;
    const int tx = threadIdx.x & 31, ty = threadIdx.x >> 5;
#pragma unroll
    for (int r = 0; r < 32; r += 8)
        tile[r + ty][tx] = W[(size_t)(k0 + r + ty) * N + n0 + tx];
    __syncthreads();
#pragma unroll
    for (int r = 0; r < 32; r += 8) {
        const int n = noff + n0 + r + ty, k = k0 + tx;
        BT[(size_t)n * KLD + k] = (_Float16)tile[tx][r + ty];
    }
}

__global__ __launch_bounds__(256) void prep_kernel(
    const float* __restrict__ hidden, const float* __restrict__ enc,
    const float* __restrict__ Wq, const float* __restrict__ Wk,
    const float* __restrict__ Wv, const float* __restrict__ Wo,
    _Float16* __restrict__ hidf, _Float16* __restrict__ encb,
    _Float16* __restrict__ B2Tq, _Float16* __restrict__ B2To,
    _Float16* __restrict__ B2Tkv)
{
    __shared__ float tile[32][33];
    int bid = blockIdx.x;
    if (bid < NB_HID) { to_f16_dev(hidden, hidf, D_MODEL, MQ, bid); return; }
    bid -= NB_HID;
    if (bid < NB_ENC) { to_f16_dev(enc, encb, DX, MKV, bid); return; }
    bid -= NB_ENC;
    if (bid < NB_WQ)  { wt_t_dev(Wq, B2Tq, D_MODEL, D_MODEL, D_MODEL, 0, bid % 40, bid / 40, tile); return; }
    bid -= NB_WQ;
    if (bid < NB_WO)  { wt_t_dev(Wo, B2To, D_MODEL, D_MODEL, D_MODEL, 0, bid % 40, bid / 40, tile); return; }
    bid -= NB_WO;
    if (bid < NB_WK)  { wt_t_dev(Wk, B2Tkv, DX, D_MODEL, DX, 0, bid % 40, bid / 40, tile); return; }
    bid -= NB_WK;
    wt_t_dev(Wv, B2Tkv, DX, D_MODEL, DX, D_MODEL, bid % 40, bid / 40, tile);
}

// ---------------------------------------------------------------------------
// MFMA fp16 GEMM (round-6 PROVEN binary: single compiled kernel, runtime mode
// branches in epilogue only, VGPR 84, 47 us on the 8192x1280x1280 shape).
// 128x128 tile, BK=64, 4 waves, single 32KB LDS, stage->barrier->compute->
// barrier, T2 pre-swizzled-source + XOR'd ds_read, T1 bijective XCD swizzle.
// LESSONS baked in: (r5) no 64KB double-buffer -- occupancy loss beats overlap;
// (r8) never inline the body at 2 call sites; (r9) no runtime operand ternaries
// feeding one call site; (r10) no template instantiations -- co-compiled
// copies perturb regalloc (VGPR 84->88, MfmaUtil 21.9->16.4, +28% time).
// Output modes: kout!=0 -> K f16 / V fp32 split (rows guarded); else Cb!=0 ->
// f16 store; else Cf fp32 + bias.
// ---------------------------------------------------------------------------
__device__ inline void async_copy16(const void* gptr, void* lptr) {
    __builtin_amdgcn_global_load_lds(
        (const __attribute__((address_space(1))) unsigned*)gptr,
        (__attribute__((address_space(3))) unsigned*)lptr, 16, 0, 0);
}

__global__ __launch_bounds__(256) void gemm_mfma_bt(
    const _Float16* __restrict__ A, const _Float16* __restrict__ B,
    float* __restrict__ Cf, _Float16* __restrict__ Cb,
    _Float16* __restrict__ kout, float* __restrict__ vout,
    int Mreal, int N, int KK, int ntn, const float* __restrict__ bias)
{
    __shared__ __align__(16) _Float16 As[128 * 64];  // 16 KB
    __shared__ __align__(16) _Float16 Bs[128 * 64];  // 16 KB
    const int t = threadIdx.x;
    const int wave = t >> 6, lane = t & 63;
    const int lr = lane & 15, lg = lane >> 4;
    const int wr = wave >> 1, wc = wave & 1;

    // T1 bijective XCD-chunk swizzle (m204)
    const int nwg = gridDim.x;
    const int q = nwg >> 3, r = nwg & 7;
    const int xcd = blockIdx.x & 7, idx = blockIdx.x >> 3;
    const int swz = (xcd < r ? xcd * (q + 1) : r * (q + 1) + (xcd - r) * q) + idx;
    const int m0 = (swz / ntn) * 128, n0 = (swz % ntn) * 128;

    f32x4 acc[4][4] = {};

    const int sr = lane >> 3;                   // row within staging instr
    const int sk = 8 * ((lane & 7) ^ sr);       // T2 pre-swizzled k-elem offset

    for (int k0 = 0; k0 < KK; k0 += 64) {
        __syncthreads();   // previous compute done
#pragma unroll
        for (int s = 0; s < 4; ++s) {
            const int ti = wave * 4 + s;
            const int row = ti * 8 + sr;
            async_copy16(A + (size_t)(m0 + row) * KK + k0 + sk, As + ti * 512);
            async_copy16(B + (size_t)(n0 + row) * KK + k0 + sk, Bs + ti * 512);
        }
        __syncthreads();   // staging complete (barrier drains vmcnt)

        f16x8 af[4][2], bf_[4][2];
#pragma unroll
        for (int i = 0; i < 4; ++i)
#pragma unroll
            for (int ki = 0; ki < 2; ++ki) {
                const int koff = (ki * 32 + lg * 8) ^ ((lr & 7) * 8);
                af[i][ki]  = *(const f16x8*)(As + (wr * 64 + i * 16 + lr) * 64 + koff);
                bf_[i][ki] = *(const f16x8*)(Bs + (wc * 64 + i * 16 + lr) * 64 + koff);
            }
#pragma unroll
        for (int ki = 0; ki < 2; ++ki)
#pragma unroll
            for (int i = 0; i < 4; ++i)
#pragma unroll
                for (int j = 0; j < 4; ++j)
                    acc[i][j] = __builtin_amdgcn_mfma_f32_16x16x32_f16(
                        af[i][ki], bf_[j][ki], acc[i][j], 0, 0, 0);
    }

    // epilogue: C row = lg*4 + rr, col = lr within fragment (m89 layout)
#pragma unroll
    for (int i = 0; i < 4; ++i) {
#pragma unroll
        for (int j = 0; j < 4; ++j) {
            const int col = n0 + wc * 64 + j * 16 + lr;
            const float bv = bias ? bias[col] : 0.f;
#pragma unroll
            for (int rr = 0; rr < 4; ++rr) {
                const int row = m0 + wr * 64 + i * 16 + lg * 4 + rr;
                const float v = acc[i][j][rr] + bv;
                if (kout) {
                    if (row < Mreal) {
                        if (col < D_MODEL) kout[(size_t)row * D_MODEL + col] = (_Float16)v;
                        else               vout[(size_t)row * D_MODEL + col - D_MODEL] = v;
                    }
                } else if (Cb) {
                    Cb[(size_t)row * N + col] = (_Float16)v;
                } else {
                    Cf[(size_t)row * N + col] = v;
                }
            }
        }
    }
}

#define GQ_BLOCKS  ((MQ/128)*(D_MODEL/128))            // 640
#define GKV_BLOCKS ((MKV_PAD/128)*(2*D_MODEL/128))     // 100

// ---------------------------------------------------------------------------
// Ortho-decomp retain transform: reads fp32 V, writes f16 V.
// ---------------------------------------------------------------------------
__global__ __launch_bounds__(256) void retain_kernel(
    const float* __restrict__ vbuf, _Float16* __restrict__ vf16,
    const float* __restrict__ tv)
{
    const int l = blockIdx.x % LTXT;
    const int r = blockIdx.x / LTXT;
    const int t = threadIdx.x;

    float g00=0,g01=0,g02=0,g11=0,g12=0,g22=0,tp0=0,tp1=0,tp2=0,pp=0;
    float p_save[10], t0s[10], t1s[10], t2s[10];
#pragma unroll
    for (int it = 0; it < 10; ++it) {
        const int j   = t + it * 256;
        const int m16 = j / HD, d = j % HD;
        const int e = m16 >> 3, h = m16 & 7;
        const float T0 = tv[((size_t)(e*24 +  0 + h) * LTXT + l) * HD + d];
        const float T1 = tv[((size_t)(e*24 +  8 + h) * LTXT + l) * HD + d];
        const float T2 = tv[((size_t)(e*24 + 16 + h) * LTXT + l) * HD + d];
        const float p  = vbuf[((size_t)((e*4 + r) * LTXT + l)) * D_MODEL + h*HD + d];
        p_save[it] = p; t0s[it] = T0; t1s[it] = T1; t2s[it] = T2;
        g00 += T0*T0; g01 += T0*T1; g02 += T0*T2;
        g11 += T1*T1; g12 += T1*T2; g22 += T2*T2;
        tp0 += T0*p;  tp1 += T1*p;  tp2 += T2*p;  pp += p*p;
    }

    __shared__ float part[4][10];
    const int wave = t >> 6, lane = t & 63;
    float vals[10] = {g00,g01,g02,g11,g12,g22,tp0,tp1,tp2,pp};
#pragma unroll
    for (int i = 0; i < 10; ++i) {
        float x = vals[i];
        x += __shfl_down(x, 32); x += __shfl_down(x, 16);
        x += __shfl_down(x,  8); x += __shfl_down(x,  4);
        x += __shfl_down(x,  2); x += __shfl_down(x,  1);
        if (lane == 0) part[wave][i] = x;
    }
    __syncthreads();

    float s[10];
#pragma unroll
    for (int i = 0; i < 10; ++i)
        s[i] = part[0][i] + part[1][i] + part[2][i] + part[3][i];

    const float G[3][3] = {{s[0],s[1],s[2]},{s[1],s[3],s[4]},{s[2],s[4],s[5]}};
    const float tp[3] = {s[6], s[7], s[8]};
    const float ppv = s[9];

    float Pm[3][3];
#pragma unroll
    for (int c = 0; c < 3; ++c)
#pragma unroll
        for (int e = 0; e < 3; ++e) {
            float v = (c == e) ? 1.f : 0.f;
            if (c > e) v -= G[c][e] / G[e][e];
            Pm[c][e] = v;
        }

    const float nP = fmaxf(sqrtf(ppv), 1e-8f);
    float w[3], cosg[3];
#pragma unroll
    for (int c = 0; c < 3; ++c) {
        const float nT = fmaxf(sqrtf(G[c][c]), 1e-8f);
        const float cosv = tp[c] / (nT * nP);
        cosg[c] = 1.f / (1.f + expf(-10.f * (cosv - 0.5f)));
        float d1 = Pm[c][0]*tp[0] + Pm[c][1]*tp[1] + Pm[c][2]*tp[2];
        float d2 = 0.f;
#pragma unroll
        for (int e = 0; e < 3; ++e)
#pragma unroll
            for (int f = 0; f < 3; ++f) d2 += Pm[c][e] * Pm[c][f] * G[e][f];
        float wc = d1 / d2;
        if (isnan(wc)) wc = 0.f;
        if (l == 0)    wc = 0.f;
        w[c] = wc;
    }

    float coef[3];
#pragma unroll
    for (int e = 0; e < 3; ++e)
        coef[e] = cosg[e] * (w[0]*Pm[0][e] + w[1]*Pm[1][e] + w[2]*Pm[2][e]);

#pragma unroll
    for (int it = 0; it < 10; ++it) {
        const int j   = t + it * 256;
        const int m16 = j / HD, d = j % HD;
        const int e = m16 >> 3, h = m16 & 7;
        const float era = coef[0]*t0s[it] + coef[1]*t1s[it] + coef[2]*t2s[it];
        vf16[((size_t)((e*4 + r) * LTXT + l)) * D_MODEL + h*HD + d] =
            (_Float16)(p_save[it] - era);
    }
}

// ---------------------------------------------------------------------------
// MFMA attention (round-3 structure, f16 K/V inputs -- proven r10).
// ---------------------------------------------------------------------------
#define KSTRIDE 168
#define VSTRIDE 104
#define PSTRIDE 104

__global__ __launch_bounds__(256, 3) void attn_mfma(
    const _Float16* __restrict__ qb,     // [8192][1280] f16
    const _Float16* __restrict__ kf,     // [616][1280] f16
    const _Float16* __restrict__ vf,     // [616][1280] f16 (retained)
    _Float16* __restrict__ hs)           // [8192][1280] f16 out
{
    __shared__ _Float16 KV[160 * VSTRIDE];    // K view: [80][KSTRIDE]
    __shared__ _Float16 Ps[4][16 * PSTRIDE];
    const int bh = blockIdx.x, b = bh >> 3, h = bh & 7;
    const int qt = blockIdx.y;
    const int t = threadIdx.x, wave = t >> 6, lane = t & 63;
    const int lr = lane & 15, lg = lane >> 4;

    // stage K as [80][KSTRIDE] f16, rows >=77 zeroed
    for (int c = t; c < 1600; c += 256) {
        const int l = c / 20, d8 = (c % 20) * 8;
        f16x8 u;
#pragma unroll
        for (int i = 0; i < 8; ++i) u[i] = (_Float16)0.f;
        if (l < LTXT) u = *(const f16x8*)&kf[((size_t)(b * LTXT + l)) * D_MODEL + h * HD + d8];
        *(f16x8*)&KV[l * KSTRIDE + d8] = u;
    }
    {
        for (int i = lane; i < 256; i += 64)
            Ps[wave][(i >> 4) * PSTRIDE + 80 + (i & 15)] = (_Float16)0.f;
    }
    __syncthreads();

    const int qrow0 = b * S_LEN + qt * 64 + wave * 16;
    const _Float16* qp = qb + (size_t)(qrow0 + lr) * D_MODEL + h * HD;
    f16x8 af[5];
#pragma unroll
    for (int kt = 0; kt < 5; ++kt)
        af[kt] = *(const f16x8*)&qp[kt * 32 + lg * 8];

    f32x4 accs[5] = {};
#pragma unroll
    for (int j = 0; j < 5; ++j)
#pragma unroll
        for (int kt = 0; kt < 5; ++kt) {
            const f16x8 bf = *(const f16x8*)&KV[(j * 16 + lr) * KSTRIDE + kt * 32 + lg * 8];
            accs[j] = __builtin_amdgcn_mfma_f32_16x16x32_f16(af[kt], bf, accs[j], 0, 0, 0);
        }

    float s[5][4];
    const float scale = 0.07905694150420949f;  // 1/sqrt(160)
#pragma unroll
    for (int j = 0; j < 5; ++j)
#pragma unroll
        for (int r = 0; r < 4; ++r)
            s[j][r] = accs[j][r] * scale;
    if (lr >= 13) { s[4][0] = -1e30f; s[4][1] = -1e30f; s[4][2] = -1e30f; s[4][3] = -1e30f; }

    float rsum[4];
#pragma unroll
    for (int r = 0; r < 4; ++r) {
        float m = s[0][r];
#pragma unroll
        for (int j = 1; j < 5; ++j) m = fmaxf(m, s[j][r]);
        m = fmaxf(m, __shfl_xor(m, 1));
        m = fmaxf(m, __shfl_xor(m, 2));
        m = fmaxf(m, __shfl_xor(m, 4));
        m = fmaxf(m, __shfl_xor(m, 8));
        float sum = 0.f;
#pragma unroll
        for (int j = 0; j < 5; ++j) {
            const float p = __expf(s[j][r] - m);
            s[j][r] = p;
            sum += p;
        }
        sum += __shfl_xor(sum, 1);
        sum += __shfl_xor(sum, 2);
        sum += __shfl_xor(sum, 4);
        sum += __shfl_xor(sum, 8);
        rsum[r] = sum;
    }

#pragma unroll
    for (int j = 0; j < 5; ++j)
#pragma unroll
        for (int r = 0; r < 4; ++r)
            Ps[wave][(lg * 4 + r) * PSTRIDE + j * 16 + lr] = (_Float16)s[j][r];

    __syncthreads();   // all waves done reading K view of KV

    // stage V^T as [160][VSTRIDE] f16, key cols >=77 zeroed
    for (int c = t; c < 1920; c += 256) {
        const int l = c / 20, d8 = (c % 20) * 8;
        f16x8 vv;
#pragma unroll
        for (int i = 0; i < 8; ++i) vv[i] = (_Float16)0.f;
        if (l < LTXT) vv = *(const f16x8*)&vf[((size_t)(b * LTXT + l)) * D_MODEL + h * HD + d8];
#pragma unroll
        for (int i = 0; i < 8; ++i)
            KV[(d8 + i) * VSTRIDE + l] = vv[i];
    }
    __syncthreads();

    f16x8 pa[3];
#pragma unroll
    for (int kt = 0; kt < 3; ++kt)
        pa[kt] = *(const f16x8*)&Ps[wave][lr * PSTRIDE + kt * 32 + lg * 8];
    f32x4 acch[10] = {};
#pragma unroll
    for (int dt = 0; dt < 10; ++dt)
#pragma unroll
        for (int kt = 0; kt < 3; ++kt) {
            const f16x8 vb = *(const f16x8*)&KV[(dt * 16 + lr) * VSTRIDE + kt * 32 + lg * 8];
            acch[dt] = __builtin_amdgcn_mfma_f32_16x16x32_f16(pa[kt], vb, acch[dt], 0, 0, 0);
        }

    const float inv[4] = {1.f / rsum[0], 1.f / rsum[1], 1.f / rsum[2], 1.f / rsum[3]};
#pragma unroll
    for (int dt = 0; dt < 10; ++dt) {
        const int col = h * HD + dt * 16 + lr;
#pragma unroll
        for (int r = 0; r < 4; ++r) {
            const int row = qrow0 + lg * 4 + r;
            hs[(size_t)row * D_MODEL + col] = (_Float16)(acch[dt][r] * inv[r]);
        }
    }
}

// ---------------------------------------------------------------------------
extern "C" void kernel_launch(void* const* d_in, const int* in_sizes, int n_in,
                              void* d_out, int out_size, void* d_ws, size_t ws_size,
                              hipStream_t stream)
{
    const float* hidden = (const float*)d_in[0]; // [8,1024,1280]
    const float* enc    = (const float*)d_in[1]; // [8,77,768]
    const float* Wq     = (const float*)d_in[2]; // [1280,1280]
    const float* Wk     = (const float*)d_in[3]; // [768,1280]
    const float* Wv     = (const float*)d_in[4]; // [768,1280]
    const float* Wo     = (const float*)d_in[5]; // [1280,1280]
    const float* bo     = (const float*)d_in[6]; // [1280]
    const float* tv     = (const float*)d_in[7]; // [48,77,160]
    float* out = (float*)d_out;

    // ws layout (~81 MB, all 16B-aligned boundaries)
    _Float16* kf     = (_Float16*)d_ws;                        // [616,1280] f16 K
    float*    vbuf   = (float*)(kf + (size_t)MKV * D_MODEL);   // [616,1280] f32 V (pre-retain)
    _Float16* vf16   = (_Float16*)(vbuf + (size_t)MKV * D_MODEL); // [616,1280] f16 V (retained)
    _Float16* qf     = vf16 + (size_t)MKV * D_MODEL;           // [8192,1280]
    _Float16* hsf    = qf   + (size_t)MQ * D_MODEL;            // [8192,1280]
    _Float16* hidf   = hsf  + (size_t)MQ * D_MODEL;            // [8192,1280]
    _Float16* encb   = hidf + (size_t)MQ * D_MODEL;            // [640,768]
    _Float16* B2Tq   = encb + (size_t)MKV_PAD * DX;            // [1280,1280]
    _Float16* B2To   = B2Tq + (size_t)D_MODEL * D_MODEL;       // [1280,1280]
    _Float16* B2Tkv  = B2To + (size_t)D_MODEL * D_MODEL;       // [2560,768]

    // 1. all input conversions/transposes in one launch
    prep_kernel<<<NB_PREP, 256, 0, stream>>>(
        hidden, enc, Wq, Wk, Wv, Wo, hidf, encb, B2Tq, B2To, B2Tkv);

    // 2. Q = f16(hidden @ Wq)           (mode: Cb)
    gemm_mfma_bt<<<GQ_BLOCKS, 256, 0, stream>>>(
        hidf, B2Tq, nullptr, qf, nullptr, nullptr,
        MQ, D_MODEL, D_MODEL, D_MODEL / 128, nullptr);

    // 3. fused K|V projection           (mode: kout/vout split)
    gemm_mfma_bt<<<GKV_BLOCKS, 256, 0, stream>>>(
        encb, B2Tkv, nullptr, nullptr, kf, vbuf,
        MKV, 2 * D_MODEL, DX, 2 * D_MODEL / 128, nullptr);

    // 4. concept-erasure retain transform: fp32 V -> f16 V
    retain_kernel<<<4 * LTXT, 256, 0, stream>>>(vbuf, vf16, tv);

    // 5. MFMA attention (f16 K/V): writes hs f16
    attn_mfma<<<dim3(NBH, S_LEN / 64), 256, 0, stream>>>(qf, kf, vf16, hsf);

    // 6. out = hs @ Wo + bo             (mode: Cf + bias)
    gemm_mfma_bt<<<GQ_BLOCKS, 256, 0, stream>>>(
        hsf, B2To, out, nullptr, nullptr, nullptr,
        MQ, D_MODEL, D_MODEL, D_MODEL / 128, bo);
}

// Round 12
// 138.664 us; speedup vs baseline: 1.5346x; 1.1591x over previous
//
#include <hip/hip_runtime.h>
#include <hip/hip_bf16.h>
#include <math.h>

// Problem constants
#define BATCH   8
#define S_LEN   1024
#define D_MODEL 1280
#define DX      768
#define NH      8
#define HD      160
#define LTXT    77
#define MKV_PAD 640             // 616 padded to 128-multiple
#define MQ      (BATCH*S_LEN)   // 8192
#define MKV     (BATCH*LTXT)    // 616
#define HL      80              // per-head padded l-stride
#define NHL     640             // 8*80
#define KPAD    192             // 160 padded to 64-multiple
#define KVROWS  5184            // 64*77=4928 + slack for 128-row tile overrun

typedef _Float16 f16x8 __attribute__((ext_vector_type(8)));
typedef _Float16 f16x4 __attribute__((ext_vector_type(4)));
typedef float    f32x4 __attribute__((ext_vector_type(4)));

// ---------------------------------------------------------------------------
// Fused prep kernel: all input-only conversions + zero-fills in ONE launch.
// ---------------------------------------------------------------------------
#define NB_HID 10240   // 8192*1280/4/256
#define NB_ENC 480     // 640*768/4/256
#define NB_WQP 1600    // plain f16 copy of Wq (1280*1280/4/256)
#define NB_WOT 1600    // transpose Wo
#define NB_WK  960
#define NB_WV  960
#define NB_ZK  972     // zero kf2 (5184*192/4/256)
#define NB_ZV  972     // zero vf2
#define NB_PREP (NB_HID+NB_ENC+NB_WQP+NB_WOT+NB_WK+NB_WV+NB_ZK+NB_ZV)

__device__ inline void to_f16_dev(const float* __restrict__ X,
                                  _Float16* __restrict__ Y,
                                  int K, int Mreal, int bid)
{
    const size_t g = ((size_t)bid * 256 + threadIdx.x) * 4;
    const int row = (int)(g / K);
    float4 x = make_float4(0.f, 0.f, 0.f, 0.f);
    if (row < Mreal) x = *(const float4*)&X[g];
    f16x4 o;
    o[0] = (_Float16)x.x; o[1] = (_Float16)x.y;
    o[2] = (_Float16)x.z; o[3] = (_Float16)x.w;
    *(f16x4*)&Y[g] = o;
}

__device__ inline void zero_f16_dev(_Float16* __restrict__ Y, int bid)
{
    const size_t g = ((size_t)bid * 256 + threadIdx.x) * 4;
    f16x4 z;
    z[0] = (_Float16)0.f; z[1] = (_Float16)0.f;
    z[2] = (_Float16)0.f; z[3] = (_Float16)0.f;
    *(f16x4*)&Y[g] = z;
}

__device__ inline void wt_t_dev(const float* __restrict__ W,
                                _Float16* __restrict__ BT,
                                int K, int N, int KLD, int noff,
                                int bx, int by, float (*tile)[33])
{
    const int k0 = by * 32, n0 = bx * 32;
    const int tx = threadIdx.x & 31, ty = threadIdx.x >> 5;
#pragma unroll
    for (int r = 0; r < 32; r += 8)
        tile[r + ty][tx] = W[(size_t)(k0 + r + ty) * N + n0 + tx];
    __syncthreads();
#pragma unroll
    for (int r = 0; r < 32; r += 8) {
        const int n = noff + n0 + r + ty, k = k0 + tx;
        BT[(size_t)n * KLD + k] = (_Float16)tile[tx][r + ty];
    }
}

__global__ __launch_bounds__(256) void prep_kernel(
    const float* __restrict__ hidden, const float* __restrict__ enc,
    const float* __restrict__ Wq, const float* __restrict__ Wk,
    const float* __restrict__ Wv, const float* __restrict__ Wo,
    _Float16* __restrict__ hidf, _Float16* __restrict__ encb,
    _Float16* __restrict__ Wqp, _Float16* __restrict__ WoT,
    _Float16* __restrict__ B2Tkv,
    _Float16* __restrict__ kf2, _Float16* __restrict__ vf2)
{
    __shared__ float tile[32][33];
    int bid = blockIdx.x;
    if (bid < NB_HID) { to_f16_dev(hidden, hidf, D_MODEL, MQ, bid); return; }
    bid -= NB_HID;
    if (bid < NB_ENC) { to_f16_dev(enc, encb, DX, MKV, bid); return; }
    bid -= NB_ENC;
    if (bid < NB_WQP) { to_f16_dev(Wq, Wqp, D_MODEL, D_MODEL, bid); return; }
    bid -= NB_WQP;
    if (bid < NB_WOT) { wt_t_dev(Wo, WoT, D_MODEL, D_MODEL, D_MODEL, 0, bid % 40, bid / 40, tile); return; }
    bid -= NB_WOT;
    if (bid < NB_WK)  { wt_t_dev(Wk, B2Tkv, DX, D_MODEL, DX, 0, bid % 40, bid / 40, tile); return; }
    bid -= NB_WK;
    if (bid < NB_WV)  { wt_t_dev(Wv, B2Tkv, DX, D_MODEL, DX, D_MODEL, bid % 40, bid / 40, tile); return; }
    bid -= NB_WV;
    if (bid < NB_ZK)  { zero_f16_dev(kf2, bid); return; }
    bid -= NB_ZK;
    zero_f16_dev(vf2, bid);
}

// ---------------------------------------------------------------------------
// Hot MFMA fp16 GEMM (r6/r11 proven core, UNTOUCHED inner loop), now batched:
// C_b[M,N] = A_b[M,KK] @ B_b[N,KK]^T. blockIdx -> (batch, mt, nt) via tpb.
// 128x128 tile, BK=64, 4 waves, single 32KB LDS, T2 swizzle, T1 XCD swizzle.
// Modes (runtime, epilogue-only -- r10 lesson: no templates/dup call sites):
//   kout!=0 : K->kf2[(b8+h)77+l][KPAD] f16 / V->vout[row][1280] f32, row<Mreal
//   else    : Cf[(b*CB+row)*N+col] = v + bias
// ---------------------------------------------------------------------------
__device__ inline void async_copy16(const void* gptr, void* lptr) {
    __builtin_amdgcn_global_load_lds(
        (const __attribute__((address_space(1))) unsigned*)gptr,
        (__attribute__((address_space(3))) unsigned*)lptr, 16, 0, 0);
}

__global__ __launch_bounds__(256) void gemm_mfma_bt(
    const _Float16* __restrict__ A, const _Float16* __restrict__ B,
    float* __restrict__ Cf, _Float16* __restrict__ kout, float* __restrict__ vout,
    const float* __restrict__ bias,
    int Mreal, int N, int KK, int ntn, int tpb, int AB, int BB, int CB)
{
    __shared__ __align__(16) _Float16 As[128 * 64];  // 16 KB
    __shared__ __align__(16) _Float16 Bs[128 * 64];  // 16 KB
    const int t = threadIdx.x;
    const int wave = t >> 6, lane = t & 63;
    const int lr = lane & 15, lg = lane >> 4;
    const int wr = wave >> 1, wc = wave & 1;

    // T1 bijective XCD-chunk swizzle (m204)
    const int nwg = gridDim.x;
    const int q = nwg >> 3, r = nwg & 7;
    const int xcd = blockIdx.x & 7, idx = blockIdx.x >> 3;
    const int swz = (xcd < r ? xcd * (q + 1) : r * (q + 1) + (xcd - r) * q) + idx;
    const int b  = swz / tpb;
    const int lc = swz % tpb;
    const int m0 = (lc / ntn) * 128, n0 = (lc % ntn) * 128;
    const size_t arow0 = (size_t)b * AB + m0;
    const size_t brow0 = (size_t)b * BB + n0;

    f32x4 acc[4][4] = {};

    const int sr = lane >> 3;                   // row within staging instr
    const int sk = 8 * ((lane & 7) ^ sr);       // T2 pre-swizzled k-elem offset

    for (int k0 = 0; k0 < KK; k0 += 64) {
        __syncthreads();   // previous compute done
#pragma unroll
        for (int s = 0; s < 4; ++s) {
            const int ti = wave * 4 + s;
            const int row = ti * 8 + sr;
            async_copy16(A + (arow0 + row) * KK + k0 + sk, As + ti * 512);
            async_copy16(B + (brow0 + row) * KK + k0 + sk, Bs + ti * 512);
        }
        __syncthreads();   // staging complete (barrier drains vmcnt)

        f16x8 af[4][2], bf_[4][2];
#pragma unroll
        for (int i = 0; i < 4; ++i)
#pragma unroll
            for (int ki = 0; ki < 2; ++ki) {
                const int koff = (ki * 32 + lg * 8) ^ ((lr & 7) * 8);
                af[i][ki]  = *(const f16x8*)(As + (wr * 64 + i * 16 + lr) * 64 + koff);
                bf_[i][ki] = *(const f16x8*)(Bs + (wc * 64 + i * 16 + lr) * 64 + koff);
            }
#pragma unroll
        for (int ki = 0; ki < 2; ++ki)
#pragma unroll
            for (int i = 0; i < 4; ++i)
#pragma unroll
                for (int j = 0; j < 4; ++j)
                    acc[i][j] = __builtin_amdgcn_mfma_f32_16x16x32_f16(
                        af[i][ki], bf_[j][ki], acc[i][j], 0, 0, 0);
    }

    // epilogue: C row = lg*4 + rr, col = lr within fragment (m89 layout)
#pragma unroll
    for (int i = 0; i < 4; ++i) {
#pragma unroll
        for (int j = 0; j < 4; ++j) {
            const int col = n0 + wc * 64 + j * 16 + lr;
            const float bv = bias ? bias[col] : 0.f;
#pragma unroll
            for (int rr = 0; rr < 4; ++rr) {
                const int row = m0 + wr * 64 + i * 16 + lg * 4 + rr;
                const float v = acc[i][j][rr] + bv;
                if (kout) {
                    if (row < Mreal) {
                        if (col < D_MODEL) {
                            const int h = col / HD, d = col % HD;
                            const int bb = row / LTXT, ll = row % LTXT;
                            kout[((size_t)((bb * 8 + h) * LTXT + ll)) * KPAD + d] = (_Float16)v;
                        } else {
                            vout[(size_t)row * D_MODEL + col - D_MODEL] = v;
                        }
                    }
                } else {
                    Cf[((size_t)(b * CB + row)) * N + col] = v;
                }
            }
        }
    }
}

// ---------------------------------------------------------------------------
// Small MFMA GEMM for the rank-77 folds (S~ and V~), fully arg-driven.
// Per-(b,h): C[m,n] = sum_k A[(bh*aBH+m)*astride + h*aH + k] *
//                            B[(bh*bBH+n)*bstride + h*bH + k],  K=KPAD (3 steps)
// write to Co[(b*oB + h*oH + m)*ostride + h*oC + n] if m<Mg && n<Ng.
// Separate kernel so the hot kernel's regalloc is untouched (r10 lesson).
// ---------------------------------------------------------------------------
__global__ __launch_bounds__(256) void gemm_small(
    const _Float16* __restrict__ A, const _Float16* __restrict__ B,
    _Float16* __restrict__ Co,
    int mtn, int ntn, int Mg, int Ng,
    int astride, int bstride, int ostride,
    int aBH, int bBH, int aH, int bH,
    int oB, int oH, int oC)
{
    __shared__ __align__(16) _Float16 As[128 * 64];
    __shared__ __align__(16) _Float16 Bs[128 * 64];
    const int t = threadIdx.x;
    const int wave = t >> 6, lane = t & 63;
    const int lr = lane & 15, lg = lane >> 4;
    const int wr = wave >> 1, wc = wave & 1;

    const int nwg = gridDim.x;
    const int q = nwg >> 3, r = nwg & 7;
    const int xcd = blockIdx.x & 7, idx = blockIdx.x >> 3;
    const int swz = (xcd < r ? xcd * (q + 1) : r * (q + 1) + (xcd - r) * q) + idx;
    const int tpb = mtn * ntn;
    const int bh = swz / tpb;
    const int lc = swz % tpb;
    const int m0 = (lc / ntn) * 128, n0 = (lc % ntn) * 128;
    const int b = bh >> 3, h = bh & 7;

    const size_t abase = (size_t)bh * aBH + m0;
    const size_t bbase = (size_t)bh * bBH + n0;
    const int aoff = h * aH, boff = h * bH;

    f32x4 acc[4][4] = {};

    const int sr = lane >> 3;
    const int sk = 8 * ((lane & 7) ^ sr);

    for (int k0 = 0; k0 < KPAD; k0 += 64) {
        __syncthreads();
#pragma unroll
        for (int s = 0; s < 4; ++s) {
            const int ti = wave * 4 + s;
            const int row = ti * 8 + sr;
            async_copy16(A + (abase + row) * astride + aoff + k0 + sk, As + ti * 512);
            async_copy16(B + (bbase + row) * bstride + boff + k0 + sk, Bs + ti * 512);
        }
        __syncthreads();

        f16x8 af[4][2], bf_[4][2];
#pragma unroll
        for (int i = 0; i < 4; ++i)
#pragma unroll
            for (int ki = 0; ki < 2; ++ki) {
                const int koff = (ki * 32 + lg * 8) ^ ((lr & 7) * 8);
                af[i][ki]  = *(const f16x8*)(As + (wr * 64 + i * 16 + lr) * 64 + koff);
                bf_[i][ki] = *(const f16x8*)(Bs + (wc * 64 + i * 16 + lr) * 64 + koff);
            }
#pragma unroll
        for (int ki = 0; ki < 2; ++ki)
#pragma unroll
            for (int i = 0; i < 4; ++i)
#pragma unroll
                for (int j = 0; j < 4; ++j)
                    acc[i][j] = __builtin_amdgcn_mfma_f32_16x16x32_f16(
                        af[i][ki], bf_[j][ki], acc[i][j], 0, 0, 0);
    }

#pragma unroll
    for (int i = 0; i < 4; ++i) {
#pragma unroll
        for (int j = 0; j < 4; ++j) {
            const int n = n0 + wc * 64 + j * 16 + lr;
#pragma unroll
            for (int rr = 0; rr < 4; ++rr) {
                const int m = m0 + wr * 64 + i * 16 + lg * 4 + rr;
                if (m < Mg && n < Ng)
                    Co[((size_t)(b * oB + h * oH + m)) * ostride + h * oC + n] =
                        (_Float16)acc[i][j][rr];
            }
        }
    }
}

// ---------------------------------------------------------------------------
// Ortho-decomp retain transform: reads fp32 V [616,1280], writes f16
// vf2[(b*8+h)*77+l][KPAD] (tails pre-zeroed by prep).
// ---------------------------------------------------------------------------
__global__ __launch_bounds__(256) void retain_kernel(
    const float* __restrict__ vbuf, _Float16* __restrict__ vf2,
    const float* __restrict__ tv)
{
    const int l = blockIdx.x % LTXT;
    const int r = blockIdx.x / LTXT;
    const int t = threadIdx.x;

    float g00=0,g01=0,g02=0,g11=0,g12=0,g22=0,tp0=0,tp1=0,tp2=0,pp=0;
    float p_save[10], t0s[10], t1s[10], t2s[10];
#pragma unroll
    for (int it = 0; it < 10; ++it) {
        const int j   = t + it * 256;
        const int m16 = j / HD, d = j % HD;
        const int e = m16 >> 3, h = m16 & 7;
        const float T0 = tv[((size_t)(e*24 +  0 + h) * LTXT + l) * HD + d];
        const float T1 = tv[((size_t)(e*24 +  8 + h) * LTXT + l) * HD + d];
        const float T2 = tv[((size_t)(e*24 + 16 + h) * LTXT + l) * HD + d];
        const float p  = vbuf[((size_t)((e*4 + r) * LTXT + l)) * D_MODEL + h*HD + d];
        p_save[it] = p; t0s[it] = T0; t1s[it] = T1; t2s[it] = T2;
        g00 += T0*T0; g01 += T0*T1; g02 += T0*T2;
        g11 += T1*T1; g12 += T1*T2; g22 += T2*T2;
        tp0 += T0*p;  tp1 += T1*p;  tp2 += T2*p;  pp += p*p;
    }

    __shared__ float part[4][10];
    const int wave = t >> 6, lane = t & 63;
    float vals[10] = {g00,g01,g02,g11,g12,g22,tp0,tp1,tp2,pp};
#pragma unroll
    for (int i = 0; i < 10; ++i) {
        float x = vals[i];
        x += __shfl_down(x, 32); x += __shfl_down(x, 16);
        x += __shfl_down(x,  8); x += __shfl_down(x,  4);
        x += __shfl_down(x,  2); x += __shfl_down(x,  1);
        if (lane == 0) part[wave][i] = x;
    }
    __syncthreads();

    float s[10];
#pragma unroll
    for (int i = 0; i < 10; ++i)
        s[i] = part[0][i] + part[1][i] + part[2][i] + part[3][i];

    const float G[3][3] = {{s[0],s[1],s[2]},{s[1],s[3],s[4]},{s[2],s[4],s[5]}};
    const float tp[3] = {s[6], s[7], s[8]};
    const float ppv = s[9];

    float Pm[3][3];
#pragma unroll
    for (int c = 0; c < 3; ++c)
#pragma unroll
        for (int e = 0; e < 3; ++e) {
            float v = (c == e) ? 1.f : 0.f;
            if (c > e) v -= G[c][e] / G[e][e];
            Pm[c][e] = v;
        }

    const float nP = fmaxf(sqrtf(ppv), 1e-8f);
    float w[3], cosg[3];
#pragma unroll
    for (int c = 0; c < 3; ++c) {
        const float nT = fmaxf(sqrtf(G[c][c]), 1e-8f);
        const float cosv = tp[c] / (nT * nP);
        cosg[c] = 1.f / (1.f + expf(-10.f * (cosv - 0.5f)));
        float d1 = Pm[c][0]*tp[0] + Pm[c][1]*tp[1] + Pm[c][2]*tp[2];
        float d2 = 0.f;
#pragma unroll
        for (int e = 0; e < 3; ++e)
#pragma unroll
            for (int f = 0; f < 3; ++f) d2 += Pm[c][e] * Pm[c][f] * G[e][f];
        float wc = d1 / d2;
        if (isnan(wc)) wc = 0.f;
        if (l == 0)    wc = 0.f;
        w[c] = wc;
    }

    float coef[3];
#pragma unroll
    for (int e = 0; e < 3; ++e)
        coef[e] = cosg[e] * (w[0]*Pm[0][e] + w[1]*Pm[1][e] + w[2]*Pm[2][e]);

#pragma unroll
    for (int it = 0; it < 10; ++it) {
        const int j   = t + it * 256;
        const int m16 = j / HD, d = j % HD;
        const int e = m16 >> 3, h = m16 & 7;
        const float era = coef[0]*t0s[it] + coef[1]*t1s[it] + coef[2]*t2s[it];
        vf2[((size_t)(((e*4 + r) * 8 + h) * LTXT + l)) * KPAD + d] =
            (_Float16)(p_save[it] - era);
    }
}

// ---------------------------------------------------------------------------
// Softmax: scores f32 [8192, 640(=8 heads x 80)] -> P~ f16 same layout.
// One wave per row; 8 lanes per head (10 cols/lane); pad cols l>=77 -> 0.
// ---------------------------------------------------------------------------
__global__ __launch_bounds__(256) void softmax_kernel(
    const float* __restrict__ sc, _Float16* __restrict__ P)
{
    const int row = blockIdx.x * 4 + (threadIdx.x >> 6);
    const int lane = threadIdx.x & 63;
    const int s = lane & 7;                 // lane position within head group
    const float* rp = sc + (size_t)row * NHL + lane * 10;
    float v[10];
#pragma unroll
    for (int j = 0; j < 10; ++j) v[j] = rp[j];
    const int nreal = (s == 7) ? 7 : 10;    // lane 7 of group: cols 70..76 real

    float mx = -1e30f;
#pragma unroll
    for (int j = 0; j < 10; ++j) if (j < nreal) mx = fmaxf(mx, v[j]);
    mx = fmaxf(mx, __shfl_xor(mx, 1));
    mx = fmaxf(mx, __shfl_xor(mx, 2));
    mx = fmaxf(mx, __shfl_xor(mx, 4));

    const float scale = 0.07905694150420949f;  // 1/sqrt(160)
    float sum = 0.f;
#pragma unroll
    for (int j = 0; j < 10; ++j) {
        const float e = (j < nreal) ? __expf((v[j] - mx) * scale) : 0.f;
        v[j] = e; sum += e;
    }
    sum += __shfl_xor(sum, 1);
    sum += __shfl_xor(sum, 2);
    sum += __shfl_xor(sum, 4);
    const float inv = 1.f / sum;

    _Float16* op = P + (size_t)row * NHL + lane * 10;
#pragma unroll
    for (int j = 0; j < 5; ++j) {
        const _Float16 a = (_Float16)(v[2*j] * inv);
        const _Float16 b = (_Float16)(v[2*j+1] * inv);
        ushort2 u;
        u.x = *(const unsigned short*)&a;
        u.y = *(const unsigned short*)&b;
        *(ushort2*)(op + 2*j) = u;
    }
}

// ---------------------------------------------------------------------------
extern "C" void kernel_launch(void* const* d_in, const int* in_sizes, int n_in,
                              void* d_out, int out_size, void* d_ws, size_t ws_size,
                              hipStream_t stream)
{
    const float* hidden = (const float*)d_in[0]; // [8,1024,1280]
    const float* enc    = (const float*)d_in[1]; // [8,77,768]
    const float* Wq     = (const float*)d_in[2]; // [1280,1280]
    const float* Wk     = (const float*)d_in[3]; // [768,1280]
    const float* Wv     = (const float*)d_in[4]; // [768,1280]
    const float* Wo     = (const float*)d_in[5]; // [1280,1280]
    const float* bo     = (const float*)d_in[6]; // [1280]
    const float* tv     = (const float*)d_in[7]; // [48,77,160]
    float* out = (float*)d_out;

    // ws layout (~87 MB)
    _Float16* kf2   = (_Float16*)d_ws;                           // [5184, 192]
    _Float16* vf2   = kf2 + (size_t)KVROWS * KPAD;               // [5184, 192]
    float*    vbuf  = (float*)(vf2 + (size_t)KVROWS * KPAD);     // [616, 1280] f32
    _Float16* Wqp   = (_Float16*)(vbuf + (size_t)MKV * D_MODEL); // [1280*1280 +192]
    _Float16* WoT   = Wqp + (size_t)D_MODEL * D_MODEL + 192;     // [1280*1280 +192]
    _Float16* B2Tkv = WoT + (size_t)D_MODEL * D_MODEL + 192;     // [2560, 768]
    _Float16* encb  = B2Tkv + (size_t)2 * D_MODEL * DX;          // [640, 768]
    _Float16* Sb    = encb + (size_t)MKV_PAD * DX;               // [8*640, 1280]
    _Float16* Vt    = Sb + (size_t)BATCH * NHL * D_MODEL;        // [8*1280, 640]
    float*    scores= (float*)(Vt + (size_t)BATCH * D_MODEL * NHL); // [8192, 640] f32
    _Float16* hidf  = (_Float16*)(scores + (size_t)MQ * NHL);    // [8192, 1280]
    _Float16* Pt    = hidf;   // P~ [8192,640] aliases hidf (dead after scores-GEMM)

    // 1. conversions / transposes / zero-fills
    prep_kernel<<<NB_PREP, 256, 0, stream>>>(
        hidden, enc, Wq, Wk, Wv, Wo, hidf, encb, Wqp, WoT, B2Tkv, kf2, vf2);

    // 2. K|V projection: K -> kf2 (head-grouped f16), V -> vbuf f32
    gemm_mfma_bt<<<100, 256, 0, stream>>>(
        encb, B2Tkv, nullptr, kf2, vbuf, nullptr,
        MKV, 2 * D_MODEL, DX, 20, 100, 0, 0, 0);

    // 3. retain transform: vbuf f32 -> vf2 f16 (head-grouped)
    retain_kernel<<<4 * LTXT, 256, 0, stream>>>(vbuf, vf2, tv);

    // 4. S~T[b][h*80+l][D] = sum_d kf2 * Wq   (M=77 guarded, N=1280, K=192)
    gemm_small<<<640, 256, 0, stream>>>(
        kf2, Wqp, Sb,
        /*mtn,ntn*/ 1, 10, /*Mg,Ng*/ LTXT, D_MODEL,
        /*astride,bstride,ostride*/ KPAD, D_MODEL, D_MODEL,
        /*aBH,bBH*/ LTXT, 0, /*aH,bH*/ 0, HD,
        /*oB,oH,oC*/ NHL, HL, 0);

    // 5. V~T[b][n][h*80+l] = sum_d WoT * vf2  (M=1280, N=77 guarded, K=192)
    gemm_small<<<640, 256, 0, stream>>>(
        WoT, vf2, Vt,
        /*mtn,ntn*/ 10, 1, /*Mg,Ng*/ D_MODEL, LTXT,
        /*astride,bstride,ostride*/ D_MODEL, KPAD, NHL,
        /*aBH,bBH*/ 0, LTXT, /*aH,bH*/ HD, 0,
        /*oB,oH,oC*/ D_MODEL, 0, HL);

    // 6. scores_b = hidf_b @ S~T_b^T  (batched 8: M=1024, N=640, K=1280) f32
    gemm_mfma_bt<<<320, 256, 0, stream>>>(
        hidf, Sb, scores, nullptr, nullptr, nullptr,
        1024, NHL, D_MODEL, 5, 40, 1024, NHL, 1024);

    // 7. softmax (scale inside): scores -> P~ f16 (pads zeroed)
    softmax_kernel<<<MQ / 4, 256, 0, stream>>>(scores, Pt);

    // 8. out_b = P~_b @ V~T_b^T + bo  (batched 8: M=1024, N=1280, K=640) f32
    gemm_mfma_bt<<<640, 256, 0, stream>>>(
        Pt, Vt, out, nullptr, nullptr, bo,
        1024, D_MODEL, NHL, 10, 80, 1024, D_MODEL, 1024);
}